// Round 12
// baseline (1137.221 us; speedup 1.0000x reference)
//
#include <hip/hip_runtime.h>
#include <hip/hip_bf16.h>
#include <math.h>

#define B_  2
#define N_  384
#define D_  256
#define PD_ 64
#define L_  8
#define H_  8
#define DH_ 32
#define GR  8      // rows per GEMM block
#define IT  8      // attention i-tile

// ---------------- embed + pos-enc + LN ----------------
__global__ void embed_ln_kernel(const int* __restrict__ tokens, const float* __restrict__ tok_emb,
                                const float* __restrict__ lnw, const float* __restrict__ lnb,
                                float* __restrict__ x) {
  int row = blockIdx.x;            // b*N + n
  int n = row % N_;
  int d = threadIdx.x;             // 0..255
  int tok = tokens[row];
  float val = tok_emb[tok * D_ + d];
  int i = d >> 1;
  float dv = expf((float)(2 * i) * (-logf(10000.0f) / (float)D_));
  float ang = (float)n * dv;
  val += (d & 1) ? cosf(ang) : sinf(ang);

  __shared__ float rbuf[256];
  rbuf[d] = val; __syncthreads();
  for (int s = 128; s > 0; s >>= 1) { if (d < s) rbuf[d] += rbuf[d + s]; __syncthreads(); }
  float mean = rbuf[0] / D_;
  __syncthreads();
  rbuf[d] = val * val; __syncthreads();
  for (int s = 128; s > 0; s >>= 1) { if (d < s) rbuf[d] += rbuf[d + s]; __syncthreads(); }
  float var = rbuf[0] / D_ - mean * mean;
  float r = rsqrtf(var + 1e-5f);
  x[row * D_ + d] = (val - mean) * r * lnw[d] + lnb[d];
}

// ---------------- QKV: 8 rows/block, k-chunk 4 x col-tile 64; K transposed ----------------
// grid = (M/GR) * 3 * 4 = 1152
__global__ void qkv_kernel(const float* __restrict__ x, const float* __restrict__ Wq,
                           const float* __restrict__ Wk, const float* __restrict__ Wv,
                           float* __restrict__ q, float* __restrict__ kt, float* __restrict__ v) {
  int bid = blockIdx.x;
  int tile = bid & 3;
  int m = (bid >> 2) % 3;
  int r0 = (bid / 12) * GR;
  int tid = threadIdx.x;           // 256
  __shared__ __align__(16) float sA[GR * D_];
  __shared__ float red[4 * GR * 64];
  for (int idx = tid; idx < GR * 64; idx += 256) {
    int r = idx >> 6, lane = idx & 63;
    ((float4*)(sA + r * D_))[lane] = ((const float4*)(x + (size_t)(r0 + r) * D_))[lane];
  }
  __syncthreads();
  const float* W = (m == 0) ? Wq : (m == 1) ? Wk : Wv;
  int kc = tid >> 6, c = tid & 63;
  const float* wp = W + (size_t)(kc * 64) * D_ + tile * 64 + c;
  float a[GR];
  #pragma unroll
  for (int r = 0; r < GR; r++) a[r] = 0.f;
  for (int kk = 0; kk < 64; kk += 4) {
    float w0 = wp[(size_t)kk * D_], w1 = wp[(size_t)(kk + 1) * D_];
    float w2 = wp[(size_t)(kk + 2) * D_], w3 = wp[(size_t)(kk + 3) * D_];
    #pragma unroll
    for (int r = 0; r < GR; r++) {
      float4 h = *(const float4*)(sA + r * D_ + kc * 64 + kk);
      a[r] = fmaf(h.x, w0, fmaf(h.y, w1, fmaf(h.z, w2, fmaf(h.w, w3, a[r]))));
    }
  }
  #pragma unroll
  for (int r = 0; r < GR; r++) red[(kc * GR + r) * 64 + c] = a[r];
  __syncthreads();
  for (int idx = tid; idx < GR * 64; idx += 256) {
    int r = idx >> 6, cc = idx & 63;
    float s = red[(0 * GR + r) * 64 + cc] + red[(1 * GR + r) * 64 + cc]
            + red[(2 * GR + r) * 64 + cc] + red[(3 * GR + r) * 64 + cc];
    int col = tile * 64 + cc;
    int row = r0 + r;
    if (m == 1) {
      int b = row / N_, j = row % N_;
      int hh = col >> 5, dd = col & 31;
      kt[((size_t)(b * H_ + hh) * DH_ + dd) * N_ + j] = s;
    } else {
      float* O = (m == 0) ? q : v;
      O[(size_t)row * D_ + col] = s;
    }
  }
}

// ---------------- fused Wo-GEMM + residual + LN: x = LN(x + ao@Wo + bo) ----------------
// grid = M/2 = 384, 256 threads (2 rows/block)
__global__ void wo_ln_kernel(const float* __restrict__ ao, const float* __restrict__ Wo,
                             const float* __restrict__ bo,
                             const float* __restrict__ lnw, const float* __restrict__ lnb,
                             float* __restrict__ x) {
  int r0 = blockIdx.x * 2;
  int tid = threadIdx.x;           // 256
  int wave = tid >> 6, lane = tid & 63;
  __shared__ __align__(16) float sAO[2 * D_];
  __shared__ float wred[4][4];     // {s0,q0,s1,q1} x wave
  if (tid < 128) ((float4*)sAO)[tid] = ((const float4*)(ao + (size_t)r0 * D_))[tid];
  __syncthreads();
  const float* wp = Wo + tid;      // col = tid
  float a0 = 0.f, a1 = 0.f, a2 = 0.f, a3 = 0.f;
  float c0 = 0.f, c1 = 0.f, c2 = 0.f, c3 = 0.f;
  for (int kk = 0; kk < D_; kk += 4) {
    float w0 = wp[(size_t)kk * D_], w1 = wp[(size_t)(kk + 1) * D_];
    float w2 = wp[(size_t)(kk + 2) * D_], w3 = wp[(size_t)(kk + 3) * D_];
    float4 h0 = *(const float4*)(sAO + kk);
    float4 h1 = *(const float4*)(sAO + D_ + kk);
    a0 = fmaf(h0.x, w0, a0); a1 = fmaf(h0.y, w1, a1);
    a2 = fmaf(h0.z, w2, a2); a3 = fmaf(h0.w, w3, a3);
    c0 = fmaf(h1.x, w0, c0); c1 = fmaf(h1.y, w1, c1);
    c2 = fmaf(h1.z, w2, c2); c3 = fmaf(h1.w, w3, c3);
  }
  float bb = bo[tid];
  float v0 = x[(size_t)r0 * D_ + tid]       + bb + (a0 + a1) + (a2 + a3);
  float v1 = x[(size_t)(r0 + 1) * D_ + tid] + bb + (c0 + c1) + (c2 + c3);
  float s0 = v0, q0 = v0 * v0, s1 = v1, q1 = v1 * v1;
  #pragma unroll
  for (int off = 32; off >= 1; off >>= 1) {
    s0 += __shfl_xor(s0, off, 64); q0 += __shfl_xor(q0, off, 64);
    s1 += __shfl_xor(s1, off, 64); q1 += __shfl_xor(q1, off, 64);
  }
  if (lane == 0) {
    wred[0][wave] = s0; wred[1][wave] = q0;
    wred[2][wave] = s1; wred[3][wave] = q1;
  }
  __syncthreads();
  float S0 = wred[0][0] + wred[0][1] + wred[0][2] + wred[0][3];
  float Q0 = wred[1][0] + wred[1][1] + wred[1][2] + wred[1][3];
  float S1 = wred[2][0] + wred[2][1] + wred[2][2] + wred[2][3];
  float Q1 = wred[3][0] + wred[3][1] + wred[3][2] + wred[3][3];
  float m0 = S0 * (1.0f / D_), m1 = S1 * (1.0f / D_);
  float r0v = rsqrtf(Q0 * (1.0f / D_) - m0 * m0 + 1e-5f);
  float r1v = rsqrtf(Q1 * (1.0f / D_) - m1 * m1 + 1e-5f);
  float wv = lnw[tid], bv = lnb[tid];
  x[(size_t)r0 * D_ + tid]       = (v0 - m0) * r0v * wv + bv;
  x[(size_t)(r0 + 1) * D_ + tid] = (v1 - m1) * r1v * wv + bv;
}

// ---------------- gemm8t: C = A@W + bias (+resid), 8 rows x col-tile 32 x k-chunk 8 ----------------
// grid = (M/GR) * (Nc/32); dyn LDS = (GR*K + 2048) floats
__global__ void gemm8t_kernel(const float* __restrict__ A, const float* __restrict__ W,
                              const float* __restrict__ bias, const float* __restrict__ resid,
                              float* __restrict__ C, int K, int Nc) {
  int tiles = Nc >> 5;
  int bid = blockIdx.x;
  int tile = bid % tiles;
  int r0 = (bid / tiles) * GR;
  int tid = threadIdx.x;           // 256
  extern __shared__ __align__(16) float sA[];
  float* red = sA + GR * K;        // 2048 floats
  int K4 = K >> 2;
  for (int idx = tid; idx < GR * K4; idx += 256) {
    int r = idx / K4, kk = idx % K4;
    ((float4*)(sA + r * K))[kk] = ((const float4*)(A + (size_t)(r0 + r) * K))[kk];
  }
  __syncthreads();
  int kc = tid >> 5, c = tid & 31;     // 8 k-chunks x 32 cols
  int KC = K >> 3;
  const float* wp = W + (size_t)(kc * KC) * Nc + tile * 32 + c;
  float a[GR];
  #pragma unroll
  for (int r = 0; r < GR; r++) a[r] = 0.f;
  for (int kk = 0; kk < KC; kk += 4) {
    float w0 = wp[(size_t)kk * Nc], w1 = wp[(size_t)(kk + 1) * Nc];
    float w2 = wp[(size_t)(kk + 2) * Nc], w3 = wp[(size_t)(kk + 3) * Nc];
    #pragma unroll
    for (int r = 0; r < GR; r++) {
      float4 h = *(const float4*)(sA + r * K + kc * KC + kk);
      a[r] = fmaf(h.x, w0, fmaf(h.y, w1, fmaf(h.z, w2, fmaf(h.w, w3, a[r]))));
    }
  }
  #pragma unroll
  for (int r = 0; r < GR; r++) red[(kc * GR + r) * 32 + c] = a[r];
  __syncthreads();
  {
    int r = tid >> 5, cc = tid & 31;   // 256 = 8 rows x 32 cols
    float s = 0.f;
    #pragma unroll
    for (int k8 = 0; k8 < 8; k8++) s += red[(k8 * GR + r) * 32 + cc];
    int col = tile * 32 + cc;
    if (bias)  s += bias[col];
    if (resid) s += resid[(size_t)(r0 + r) * Nc + col];
    C[(size_t)(r0 + r) * Nc + col] = s;
  }
}

// ---------------- ff1: f = gelu(LN(x)@W1+b1); 8 rows x 8 col-tiles x 2 k-chunks ----------------
// grid = (M/GR) * 8 = 768
__global__ void ff1_kernel(const float* __restrict__ x,
                           const float* __restrict__ lnw, const float* __restrict__ lnb,
                           const float* __restrict__ W1, const float* __restrict__ b1,
                           float* __restrict__ f) {
  int bid = blockIdx.x;
  int tile = bid & 7;              // 128 cols each
  int r0 = (bid >> 3) * GR;
  int tid = threadIdx.x;
  __shared__ __align__(16) float sA[GR * D_];
  __shared__ float red[2 * GR * 128];
  // LN: 4 waves x 2 rows each
  #pragma unroll
  for (int p = 0; p < 2; p++) {
    int r = (tid >> 6) + p * 4;
    int lane = tid & 63;
    float4 v = ((const float4*)(x + (size_t)(r0 + r) * D_))[lane];
    float s = v.x + v.y + v.z + v.w;
    float s2 = v.x * v.x + v.y * v.y + v.z * v.z + v.w * v.w;
    #pragma unroll
    for (int off = 32; off >= 1; off >>= 1) {
      s  += __shfl_xor(s, off, 64);
      s2 += __shfl_xor(s2, off, 64);
    }
    float mean = s * (1.0f / D_);
    float var = s2 * (1.0f / D_) - mean * mean;
    float rin = rsqrtf(var + 1e-5f);
    float4 w4 = ((const float4*)lnw)[lane];
    float4 b4 = ((const float4*)lnb)[lane];
    float4 nv;
    nv.x = (v.x - mean) * rin * w4.x + b4.x;
    nv.y = (v.y - mean) * rin * w4.y + b4.y;
    nv.z = (v.z - mean) * rin * w4.z + b4.z;
    nv.w = (v.w - mean) * rin * w4.w + b4.w;
    ((float4*)(sA + r * D_))[lane] = nv;
  }
  __syncthreads();
  int kc = tid >> 7, c = tid & 127;   // 2 k-chunks x 128 cols
  int col = tile * 128 + c;
  const float* wp = W1 + (size_t)(kc * 128) * 1024 + col;
  float a[GR];
  #pragma unroll
  for (int r = 0; r < GR; r++) a[r] = 0.f;
  for (int kk = 0; kk < 128; kk += 4) {
    float w0 = wp[(size_t)kk * 1024], w1 = wp[(size_t)(kk + 1) * 1024];
    float w2 = wp[(size_t)(kk + 2) * 1024], w3 = wp[(size_t)(kk + 3) * 1024];
    #pragma unroll
    for (int r = 0; r < GR; r++) {
      float4 h = *(const float4*)(sA + r * D_ + kc * 128 + kk);
      a[r] = fmaf(h.x, w0, fmaf(h.y, w1, fmaf(h.z, w2, fmaf(h.w, w3, a[r]))));
    }
  }
  #pragma unroll
  for (int r = 0; r < GR; r++) red[(kc * GR + r) * 128 + c] = a[r];
  __syncthreads();
  for (int idx = tid; idx < GR * 128; idx += 256) {
    int r = idx >> 7, cc = idx & 127;
    int colw = tile * 128 + cc;
    float s = red[(0 * GR + r) * 128 + cc] + red[(1 * GR + r) * 128 + cc] + b1[colw];
    s = 0.5f * s * (1.0f + erff(s * 0.7071067811865475f));
    f[(size_t)(r0 + r) * 1024 + colw] = s;
  }
}

// ---------------- attention: i-tiled (IT=8), K/V staged in LDS once per block ----------------
// grid = B*H*(N/IT) = 768, 256 threads
__global__ void attn_kernel(const float* __restrict__ Q, const float* __restrict__ KT,
                            const float* __restrict__ V,
                            const float* __restrict__ tx, const float* __restrict__ ty,
                            const float* __restrict__ tz, float* __restrict__ AO) {
  const int TILES = N_ / IT;       // 48
  int bid = blockIdx.x;
  int it = bid % TILES;
  int h  = (bid / TILES) % H_;
  int b  = bid / (TILES * H_);
  int i0 = it * IT;
  int tid = threadIdx.x;
  int wave = tid >> 6, lane = tid & 63;

  __shared__ __align__(16) float sQ[IT * DH_];   // 1 KB
  __shared__ __align__(16) float sK[DH_ * 64];   // 8 KB
  __shared__ __align__(16) float sV[64 * DH_];   // 8 KB
  __shared__ float sS[IT][N_];                   // 12 KB
  __shared__ float sti[3][IT];
  __shared__ float sinv[IT];

  {
    int ii = tid >> 5, d = tid & 31;             // 256 = 8*32
    sQ[ii * DH_ + d] = Q[((size_t)(b * N_ + i0 + ii)) * D_ + h * DH_ + d];
  }
  if (tid < IT) {
    sti[0][tid] = tx[b * N_ + i0 + tid];
    sti[1][tid] = ty[b * N_ + i0 + tid];
    sti[2][tid] = tz[b * N_ + i0 + tid];
  }
  const float* ktb = KT + (size_t)(b * H_ + h) * DH_ * N_;
  const float* vb  = V + (size_t)b * N_ * D_ + h * DH_;
  const float* txb = tx + b * N_;
  const float* tyb = ty + b * N_;
  const float* tzb = tz + b * N_;
  __syncthreads();

  // ---- scores, j-chunks of 64; wave handles rows wave*2, wave*2+1 ----
  for (int jc = 0; jc < N_; jc += 64) {
    for (int idx = tid; idx < DH_ * 64; idx += 256) {
      int d = idx >> 6, jj = idx & 63;
      sK[d * 64 + jj] = ktb[(size_t)d * N_ + jc + jj];
    }
    __syncthreads();
    int jj = lane;
    float tjx = txb[jc + jj], tjy = tyb[jc + jj], tjz = tzb[jc + jj];
    const float* q0 = sQ + (wave * 2 + 0) * DH_;
    const float* q1 = sQ + (wave * 2 + 1) * DH_;
    float a0 = 0.f, a1 = 0.f;
    #pragma unroll 8
    for (int d = 0; d < DH_; d++) {
      float kv = sK[d * 64 + jj];
      a0 = fmaf(q0[d], kv, a0);
      a1 = fmaf(q1[d], kv, a1);
    }
    #pragma unroll
    for (int s = 0; s < 2; s++) {
      int ii = wave * 2 + s;
      float a = (s == 0) ? a0 : a1;
      float dx = sti[0][ii] - tjx;
      float dy = sti[1][ii] - tjy;
      float dz = sti[2][ii] - tjz;
      sS[ii][jc + jj] = a * 0.17677669529663689f - (dx * dx + dy * dy + dz * dz);
    }
    __syncthreads();
  }

  // ---- softmax over full rows ----
  #pragma unroll
  for (int s = 0; s < 2; s++) {
    int ii = wave * 2 + s;
    float vrow[6];
    float m = -1e30f;
    #pragma unroll
    for (int t = 0; t < 6; t++) { vrow[t] = sS[ii][t * 64 + lane]; m = fmaxf(m, vrow[t]); }
    #pragma unroll
    for (int off = 32; off >= 1; off >>= 1) m = fmaxf(m, __shfl_xor(m, off, 64));
    float ps = 0.f;
    #pragma unroll
    for (int t = 0; t < 6; t++) {
      float e = expf(vrow[t] - m);
      sS[ii][t * 64 + lane] = e;
      ps += e;
    }
    #pragma unroll
    for (int off = 32; off >= 1; off >>= 1) ps += __shfl_xor(ps, off, 64);
    if (lane == 0) sinv[ii] = 1.0f / ps;
  }
  __syncthreads();

  // ---- PV: one output per thread (ii = tid>>5, dd = tid&31), 2 parity accs ----
  int ii = tid >> 5, dd = tid & 31;
  float o0 = 0.f, o1 = 0.f;
  for (int jc = 0; jc < N_; jc += 64) {
    for (int idx = tid; idx < 64 * DH_; idx += 256) {
      int jj = idx >> 5, d = idx & 31;
      sV[jj * DH_ + d] = vb[(size_t)(jc + jj) * D_ + d];
    }
    __syncthreads();
    #pragma unroll 8
    for (int jj = 0; jj < 64; jj += 2) {
      o0 = fmaf(sS[ii][jc + jj],     sV[jj * DH_ + dd],       o0);
      o1 = fmaf(sS[ii][jc + jj + 1], sV[(jj + 1) * DH_ + dd], o1);
    }
    __syncthreads();
  }
  AO[((size_t)(b * N_ + i0 + ii)) * D_ + h * DH_ + dd] = (o0 + o1) * sinv[ii];
}

// ---------------- proj = relu(x@Wop+bop) + row mean; 4 k-chunks x 64 cols ----------------
// grid = M, 256 threads
__global__ void proj_mean_kernel(const float* __restrict__ x, const float* __restrict__ Wop,
                                 const float* __restrict__ bop,
                                 float* __restrict__ proj, float* __restrict__ mp) {
  int row = blockIdx.x;
  int tid = threadIdx.x;           // 256
  __shared__ __align__(16) float sA[D_];
  __shared__ float red[4][PD_];
  if (tid < 64) ((float4*)sA)[tid] = ((const float4*)(x + (size_t)row * D_))[tid];
  __syncthreads();
  int kc = tid >> 6, c = tid & 63;
  const float* wp = Wop + (kc * 64) * PD_ + c;
  const float* s0 = sA + kc * 64;
  float a0 = 0.f, a1 = 0.f, a2 = 0.f, a3 = 0.f;
  for (int kk = 0; kk < 64; kk += 4) {
    a0 = fmaf(s0[kk],     wp[(kk)     * PD_], a0);
    a1 = fmaf(s0[kk + 1], wp[(kk + 1) * PD_], a1);
    a2 = fmaf(s0[kk + 2], wp[(kk + 2) * PD_], a2);
    a3 = fmaf(s0[kk + 3], wp[(kk + 3) * PD_], a3);
  }
  red[kc][c] = (a0 + a1) + (a2 + a3);
  __syncthreads();
  if (tid < 64) {
    float acc = fmaxf(bop[tid] + red[0][tid] + red[1][tid] + red[2][tid] + red[3][tid], 0.0f);
    proj[row * PD_ + tid] = acc;
    float s = acc;
    #pragma unroll
    for (int off = 32; off >= 1; off >>= 1) s += __shfl_xor(s, off, 64);
    if (tid == 0) mp[row] = s * (1.0f / PD_);
  }
}

// ---------------- rel row means (once per launch) ----------------
__global__ void rel_mean_kernel(const float* __restrict__ relpos, float* __restrict__ mr) {
  int r = blockIdx.x;              // 129
  int c = threadIdx.x;             // 64
  float s = relpos[r * PD_ + c];
  #pragma unroll
  for (int off = 32; off >= 1; off >>= 1) s += __shfl_xor(s, off, 64);
  if (c == 0) mr[r] = s * (1.0f / PD_);
}

// ---------------- fused pair LN-mean + head ----------------
// grid = M, 256 threads
__global__ void pair_head_kernel(const float* __restrict__ proj, const float* __restrict__ relpos,
                                 const float* __restrict__ mp, const float* __restrict__ mr,
                                 const float* __restrict__ lnw, const float* __restrict__ lnb,
                                 const float* __restrict__ x,
                                 const float* __restrict__ Wf1, const float* __restrict__ bWf1,
                                 const float* __restrict__ Wf2, const float* __restrict__ bWf2,
                                 float* __restrict__ frames, float* __restrict__ tx,
                                 float* __restrict__ ty, float* __restrict__ tz) {
  int row = blockIdx.x;            // b*N + i
  int b = row / N_;
  int i = row % N_;
  int tid = threadIdx.x;           // 256 = 4 waves
  int lane = tid & 63;
  int wave = tid >> 6;
  __shared__ float red[4][PD_];
  __shared__ float sfeat[320];
  __shared__ float fred[2][128];
  __shared__ float sg[128];
  __shared__ float sraw[9];

  // ---- phase 1: pair LN + mean over j (analytic mean) ----
  float vpi = proj[row * PD_ + lane];
  float mpi = mp[row];
  const float* pb  = proj + (size_t)b * N_ * PD_;
  const float* mpb = mp + b * N_;
  float acc = 0.0f;
  for (int j = wave * 2; j < N_; j += 8) {
    int ja = j, jb = j + 1;
    int ra = ja - i; ra = ra < -64 ? -64 : (ra > 64 ? 64 : ra); ra += 64;
    int rb = jb - i; rb = rb < -64 ? -64 : (rb > 64 ? 64 : rb); rb += 64;
    float va = vpi + pb[ja * PD_ + lane] + relpos[ra * PD_ + lane];
    float vb = vpi + pb[jb * PD_ + lane] + relpos[rb * PD_ + lane];
    float da = va - (mpi + mpb[ja] + mr[ra]);
    float db = vb - (mpi + mpb[jb] + mr[rb]);
    float s2a = da * da, s2b = db * db;
    #pragma unroll
    for (int off = 32; off >= 1; off >>= 1) {
      s2a += __shfl_xor(s2a, off, 64);
      s2b += __shfl_xor(s2b, off, 64);
    }
    float rinva = rsqrtf(s2a * (1.0f / PD_) + 1e-5f);
    float rinvb = rsqrtf(s2b * (1.0f / PD_) + 1e-5f);
    acc += da * rinva + db * rinvb;
  }
  red[wave][lane] = acc;
  if (tid < D_) sfeat[tid] = x[(size_t)row * D_ + tid];
  __syncthreads();
  if (wave == 0) {
    float s = red[0][lane] + red[1][lane] + red[2][lane] + red[3][lane];
    sfeat[D_ + lane] = lnb[lane] + s * lnw[lane] * (1.0f / N_);
  }
  __syncthreads();

  // ---- phase 2: fc1 silu (320 -> 128), 2 k-chunks x 128 cols ----
  int kc = tid >> 7, c = tid & 127;
  int koff = kc * 160;
  const float* wp = Wf1 + (size_t)koff * 128 + c;
  const float* s0 = sfeat + koff;
  float a0 = 0.f, a1 = 0.f, a2 = 0.f, a3 = 0.f;
  for (int kk = 0; kk < 160; kk += 4) {
    a0 = fmaf(s0[kk],     wp[(size_t)kk * 128],       a0);
    a1 = fmaf(s0[kk + 1], wp[(size_t)(kk + 1) * 128], a1);
    a2 = fmaf(s0[kk + 2], wp[(size_t)(kk + 2) * 128], a2);
    a3 = fmaf(s0[kk + 3], wp[(size_t)(kk + 3) * 128], a3);
  }
  fred[kc][c] = (a0 + a1) + (a2 + a3);
  __syncthreads();
  if (tid < 128) {
    float g = fred[0][tid] + fred[1][tid] + bWf1[tid];
    sg[tid] = g / (1.0f + expf(-g));   // silu
  }
  __syncthreads();

  // ---- phase 3: fc2 (128 -> 9), rot6d, frame write ----
  if (tid < 9) {
    float b0 = 0.f, b1v = 0.f;
    for (int kk = 0; kk < 128; kk += 2) {
      b0  = fmaf(sg[kk],     Wf2[(kk)     * 9 + tid], b0);
      b1v = fmaf(sg[kk + 1], Wf2[(kk + 1) * 9 + tid], b1v);
    }
    sraw[tid] = bWf2[tid] + b0 + b1v;
  }
  __syncthreads();
  if (tid == 0) {
    float a1x = sraw[0], a1y = sraw[1], a1z = sraw[2];
    float a2x = sraw[3], a2y = sraw[4], a2z = sraw[5];
    float n1 = sqrtf(a1x * a1x + a1y * a1y + a1z * a1z + 1e-8f);
    float b1x = a1x / n1, b1y = a1y / n1, b1z = a1z / n1;
    float dp = b1x * a2x + b1y * a2y + b1z * a2z;
    float px = a2x - dp * b1x, py = a2y - dp * b1y, pz = a2z - dp * b1z;
    float n2 = sqrtf(px * px + py * py + pz * pz + 1e-8f);
    float b2x = px / n2, b2y = py / n2, b2z = pz / n2;
    float b3x = b1y * b2z - b1z * b2y;
    float b3y = b1z * b2x - b1x * b2z;
    float b3z = b1x * b2y - b1y * b2x;
    float* f = frames + row * 16;
    f[0]  = b1x; f[1]  = b1y; f[2]  = b1z; f[3]  = sraw[6];
    f[4]  = b2x; f[5]  = b2y; f[6]  = b2z; f[7]  = sraw[7];
    f[8]  = b3x; f[9]  = b3y; f[10] = b3z; f[11] = sraw[8];
    f[12] = 0.0f; f[13] = 0.0f; f[14] = 0.0f; f[15] = 1.0f;
    tx[row] = sraw[6];
    ty[row] = sraw[7];
    tz[row] = sraw[8];
  }
}

// ---------------- init / output ----------------
__global__ void init_kernel(float* __restrict__ frames, float* __restrict__ tx,
                            float* __restrict__ ty, float* __restrict__ tz) {
  int i = blockIdx.x * 256 + threadIdx.x;
  if (i < B_ * N_ * 16) {
    int p = i & 15;
    frames[i] = (p == 0 || p == 5 || p == 10 || p == 15) ? 1.0f : 0.0f;
  }
  if (i < B_ * N_) { tx[i] = 0.0f; ty[i] = 0.0f; tz[i] = 0.0f; }
}

__global__ void write_out_kernel(const float* __restrict__ frames, const float* __restrict__ x,
                                 float* __restrict__ out) {
  int i = blockIdx.x * 256 + threadIdx.x;
  const int nf = B_ * N_ * 16;
  const int total = nf + B_ * N_ * D_;
  if (i < nf) out[i] = frames[i];
  else if (i < total) out[i] = x[i - nf];
}

extern "C" void kernel_launch(void* const* d_in, const int* in_sizes, int n_in,
                              void* d_out, int out_size, void* d_ws, size_t ws_size,
                              hipStream_t stream) {
  const int*   tokens    = (const int*)  d_in[0];
  const float* tok_emb   = (const float*)d_in[1];
  const float* emb_ln_w  = (const float*)d_in[2];
  const float* emb_ln_b  = (const float*)d_in[3];
  const float* Wq        = (const float*)d_in[4];
  const float* Wk        = (const float*)d_in[5];
  const float* Wv        = (const float*)d_in[6];
  const float* Wo        = (const float*)d_in[7];
  const float* bo        = (const float*)d_in[8];
  const float* attn_ln_w = (const float*)d_in[9];
  const float* attn_ln_b = (const float*)d_in[10];
  const float* ff_ln_w   = (const float*)d_in[11];
  const float* ff_ln_b   = (const float*)d_in[12];
  const float* W1        = (const float*)d_in[13];
  const float* b1        = (const float*)d_in[14];
  const float* W2        = (const float*)d_in[15];
  const float* b2        = (const float*)d_in[16];
  const float* Wop       = (const float*)d_in[17];
  const float* bop       = (const float*)d_in[18];
  const float* relpos    = (const float*)d_in[19];
  const float* pair_ln_w = (const float*)d_in[20];
  const float* pair_ln_b = (const float*)d_in[21];
  const float* Wf1       = (const float*)d_in[22];
  const float* bWf1      = (const float*)d_in[23];
  const float* Wf2       = (const float*)d_in[24];
  const float* bWf2      = (const float*)d_in[25];

  const int M = B_ * N_;           // 768
  const int XE = M * D_;           // 196608
  float* ws     = (float*)d_ws;
  float* frames = ws;                      // 12288
  float* proj   = frames + M * 16;         // 49152
  float* mp     = proj   + M * PD_;        // 768
  float* mr     = mp     + M;              // 129 (pad 192)
  float* tx     = mr     + 192;            // 768
  float* ty     = tx     + M;              // 768
  float* tz     = ty     + M;              // 768
  float* x      = tz     + M;              // XE
  float* q      = x  + XE;                 // XE
  float* kt     = q  + XE;                 // XE (K transposed [b,h,d,j])
  float* v      = kt + XE;                 // XE
  float* ao     = v  + XE;                 // XE
  float* f      = q;                       // alias: q..ao = 4*XE (ff intermediate)
  // total ≈ 4.2 MB

  embed_ln_kernel<<<M, 256, 0, stream>>>(tokens, tok_emb, emb_ln_w, emb_ln_b, x);
  init_kernel<<<(M * 16 + 255) / 256, 256, 0, stream>>>(frames, tx, ty, tz);
  rel_mean_kernel<<<129, 64, 0, stream>>>(relpos, mr);

  const size_t lds_ff2 = (GR * 1024 + 2048) * sizeof(float);   // 40 KB

  for (int l = 0; l < L_; l++) {
    qkv_kernel<<<(M / GR) * 12, 256, 0, stream>>>(x, Wq + (size_t)l * D_ * D_,
                                                  Wk + (size_t)l * D_ * D_,
                                                  Wv + (size_t)l * D_ * D_, q, kt, v);
    attn_kernel<<<B_ * H_ * (N_ / IT), 256, 0, stream>>>(q, kt, v, tx, ty, tz, ao);
    wo_ln_kernel<<<M / 2, 256, 0, stream>>>(ao, Wo + (size_t)l * D_ * D_, bo + l * D_,
                                            attn_ln_w + l * D_, attn_ln_b + l * D_, x);
    // ff: f = gelu(LN(x)@W1+b1)  [f aliases q..ao];  x += f@W2+b2
    ff1_kernel<<<(M / GR) * 8, 256, 0, stream>>>(x, ff_ln_w + l * D_, ff_ln_b + l * D_,
                                                 W1 + (size_t)l * D_ * 1024, b1 + l * 1024, f);
    gemm8t_kernel<<<(M / GR) * 8, 256, lds_ff2, stream>>>(
        f, W2 + (size_t)l * 1024 * D_, b2 + l * D_, x, x, 1024, D_);
    proj_mean_kernel<<<M, 256, 0, stream>>>(x, Wop, bop, proj, mp);
    pair_head_kernel<<<M, 256, 0, stream>>>(proj, relpos, mp, mr, pair_ln_w, pair_ln_b,
                                            x, Wf1, bWf1, Wf2, bWf2, frames, tx, ty, tz);
  }

  const int total = B_ * N_ * 16 + B_ * N_ * D_;
  write_out_kernel<<<(total + 255) / 256, 256, 0, stream>>>(frames, x, (float*)d_out);
}

// Round 13
// 1077.176 us; speedup vs baseline: 1.0557x; 1.0557x over previous
//
#include <hip/hip_runtime.h>
#include <hip/hip_bf16.h>
#include <math.h>

#define B_  2
#define N_  384
#define D_  256
#define PD_ 64
#define L_  8
#define H_  8
#define DH_ 32
#define GR  4      // rows per GEMM block
#define IT  8      // attention i-tile

// ---------------- prologue: embed + pos-enc + LN, frames/t init, rel means ----------------
// grid = M, 256 threads
__global__ void prologue_kernel(const int* __restrict__ tokens, const float* __restrict__ tok_emb,
                                const float* __restrict__ lnw, const float* __restrict__ lnb,
                                const float* __restrict__ relpos,
                                float* __restrict__ x, float* __restrict__ frames,
                                float* __restrict__ tx, float* __restrict__ ty,
                                float* __restrict__ tz, float* __restrict__ mr) {
  int row = blockIdx.x;            // b*N + n
  int n = row % N_;
  int d = threadIdx.x;             // 0..255
  // frames = I, t = 0
  if (d < 16) frames[row * 16 + d] = (d == 0 || d == 5 || d == 10 || d == 15) ? 1.0f : 0.0f;
  if (d == 16) tx[row] = 0.0f;
  if (d == 17) ty[row] = 0.0f;
  if (d == 18) tz[row] = 0.0f;
  // rel row means: wave 3 of blocks 0..128
  if (row < 129 && d >= 192) {
    int lane = d & 63;
    float s = relpos[row * PD_ + lane];
    #pragma unroll
    for (int off = 32; off >= 1; off >>= 1) s += __shfl_xor(s, off, 64);
    if (lane == 0) mr[row] = s * (1.0f / PD_);
  }
  // embed + pos-enc + LN
  int tok = tokens[row];
  float val = tok_emb[tok * D_ + d];
  int i = d >> 1;
  float dv = expf((float)(2 * i) * (-logf(10000.0f) / (float)D_));
  float ang = (float)n * dv;
  val += (d & 1) ? cosf(ang) : sinf(ang);
  __shared__ float rbuf[256];
  rbuf[d] = val; __syncthreads();
  for (int s = 128; s > 0; s >>= 1) { if (d < s) rbuf[d] += rbuf[d + s]; __syncthreads(); }
  float mean = rbuf[0] / D_;
  __syncthreads();
  rbuf[d] = val * val; __syncthreads();
  for (int s = 128; s > 0; s >>= 1) { if (d < s) rbuf[d] += rbuf[d + s]; __syncthreads(); }
  float var = rbuf[0] / D_ - mean * mean;
  float r = rsqrtf(var + 1e-5f);
  x[row * D_ + d] = (val - mean) * r * lnw[d] + lnb[d];
}

// ---------------- qkv unit (GR=4, k-chunk 4 x col-tile 64; K transposed) ----------------
// units = (M/GR)*12 = 2304; smem >= 2048 floats
__device__ __forceinline__ void qkv_unit(int bid, int tid, const float* __restrict__ x,
                                         const float* __restrict__ Wq, const float* __restrict__ Wk,
                                         const float* __restrict__ Wv,
                                         float* __restrict__ q, float* __restrict__ kt,
                                         float* __restrict__ v, float* sA) {
  int tile = bid & 3;
  int m = (bid >> 2) % 3;
  int r0 = (bid / 12) * GR;
  float* red = sA + GR * D_;       // 1024 floats
  {
    int r = tid >> 6, lane = tid & 63;
    ((float4*)(sA + r * D_))[lane] = ((const float4*)(x + (size_t)(r0 + r) * D_))[lane];
  }
  __syncthreads();
  const float* W = (m == 0) ? Wq : (m == 1) ? Wk : Wv;
  int kc = tid >> 6, c = tid & 63;
  const float* wp = W + (size_t)(kc * 64) * D_ + tile * 64 + c;
  const float* s0 = sA + kc * 64;
  float a0 = 0.f, a1 = 0.f, a2 = 0.f, a3 = 0.f;
  for (int kk = 0; kk < 64; kk += 4) {
    float w0 = wp[(size_t)kk * D_], w1 = wp[(size_t)(kk + 1) * D_];
    float w2 = wp[(size_t)(kk + 2) * D_], w3 = wp[(size_t)(kk + 3) * D_];
    float4 h0 = *(const float4*)(s0 + 0 * D_ + kk);
    float4 h1 = *(const float4*)(s0 + 1 * D_ + kk);
    float4 h2 = *(const float4*)(s0 + 2 * D_ + kk);
    float4 h3 = *(const float4*)(s0 + 3 * D_ + kk);
    a0 = fmaf(h0.x, w0, fmaf(h0.y, w1, fmaf(h0.z, w2, fmaf(h0.w, w3, a0))));
    a1 = fmaf(h1.x, w0, fmaf(h1.y, w1, fmaf(h1.z, w2, fmaf(h1.w, w3, a1))));
    a2 = fmaf(h2.x, w0, fmaf(h2.y, w1, fmaf(h2.z, w2, fmaf(h2.w, w3, a2))));
    a3 = fmaf(h3.x, w0, fmaf(h3.y, w1, fmaf(h3.z, w2, fmaf(h3.w, w3, a3))));
  }
  red[(kc * 4 + 0) * 64 + c] = a0;
  red[(kc * 4 + 1) * 64 + c] = a1;
  red[(kc * 4 + 2) * 64 + c] = a2;
  red[(kc * 4 + 3) * 64 + c] = a3;
  __syncthreads();
  int r = tid >> 6;
  float s = red[(0 * 4 + r) * 64 + c] + red[(1 * 4 + r) * 64 + c]
          + red[(2 * 4 + r) * 64 + c] + red[(3 * 4 + r) * 64 + c];
  int col = tile * 64 + c;
  int row = r0 + r;
  if (m == 1) {
    int b = row / N_, j = row % N_;
    int hh = col >> 5, dd = col & 31;
    kt[((size_t)(b * H_ + hh) * DH_ + dd) * N_ + j] = s;
  } else {
    float* O = (m == 0) ? q : v;
    O[(size_t)row * D_ + col] = s;
  }
}

// ---------------- proj unit: proj = relu(x@Wop+bop) + row mean; 4 k-chunks x 64 cols ----
// smem >= 512 floats
__device__ __forceinline__ void proj_unit(int row, int tid, const float* __restrict__ x,
                                          const float* __restrict__ Wop, const float* __restrict__ bop,
                                          float* __restrict__ proj, float* __restrict__ mp,
                                          float* smem) {
  float* sA  = smem;               // 256
  float* red = smem + 256;         // 256
  if (tid < 64) ((float4*)sA)[tid] = ((const float4*)(x + (size_t)row * D_))[tid];
  __syncthreads();
  int kc = tid >> 6, c = tid & 63;
  const float* wp = Wop + (kc * 64) * PD_ + c;
  const float* s0 = sA + kc * 64;
  float a0 = 0.f, a1 = 0.f, a2 = 0.f, a3 = 0.f;
  for (int kk = 0; kk < 64; kk += 4) {
    a0 = fmaf(s0[kk],     wp[(kk)     * PD_], a0);
    a1 = fmaf(s0[kk + 1], wp[(kk + 1) * PD_], a1);
    a2 = fmaf(s0[kk + 2], wp[(kk + 2) * PD_], a2);
    a3 = fmaf(s0[kk + 3], wp[(kk + 3) * PD_], a3);
  }
  red[kc * 64 + c] = (a0 + a1) + (a2 + a3);
  __syncthreads();
  if (tid < 64) {
    float acc = fmaxf(bop[tid] + red[tid] + red[64 + tid] + red[128 + tid] + red[192 + tid], 0.0f);
    proj[row * PD_ + tid] = acc;
    float s = acc;
    #pragma unroll
    for (int off = 32; off >= 1; off >>= 1) s += __shfl_xor(s, off, 64);
    if (tid == 0) mp[row] = s * (1.0f / PD_);
  }
}

// ---------------- standalone qkv (layer 0) ----------------
__global__ void qkv_kernel(const float* __restrict__ x, const float* __restrict__ Wq,
                           const float* __restrict__ Wk, const float* __restrict__ Wv,
                           float* __restrict__ q, float* __restrict__ kt, float* __restrict__ v) {
  __shared__ __align__(16) float smem[2048];
  qkv_unit(blockIdx.x, threadIdx.x, x, Wq, Wk, Wv, q, kt, v, smem);
}

// ---------------- combined proj(l) + qkv(l+1): both read only x ----------------
// grid = 768 (+ 2304 when qkv included)
__global__ void proj_qkv_kernel(const float* __restrict__ x,
                                const float* __restrict__ Wop, const float* __restrict__ bop,
                                float* __restrict__ proj, float* __restrict__ mp,
                                const float* __restrict__ Wq, const float* __restrict__ Wk,
                                const float* __restrict__ Wv,
                                float* __restrict__ q, float* __restrict__ kt,
                                float* __restrict__ v) {
  __shared__ __align__(16) float smem[2048];
  int bid = blockIdx.x, tid = threadIdx.x;
  if (bid < B_ * N_) proj_unit(bid, tid, x, Wop, bop, proj, mp, smem);
  else               qkv_unit(bid - B_ * N_, tid, x, Wq, Wk, Wv, q, kt, v, smem);
}

// ---------------- fused Wo-GEMM + residual + LN: x = LN(x + ao@Wo + bo) ----------------
// grid = M/2 = 384, 256 threads (2 rows/block)
__global__ void wo_ln_kernel(const float* __restrict__ ao, const float* __restrict__ Wo,
                             const float* __restrict__ bo,
                             const float* __restrict__ lnw, const float* __restrict__ lnb,
                             float* __restrict__ x) {
  int r0 = blockIdx.x * 2;
  int tid = threadIdx.x;           // 256
  int wave = tid >> 6, lane = tid & 63;
  __shared__ __align__(16) float sAO[2 * D_];
  __shared__ float wred[4][4];
  if (tid < 128) ((float4*)sAO)[tid] = ((const float4*)(ao + (size_t)r0 * D_))[tid];
  __syncthreads();
  const float* wp = Wo + tid;      // col = tid
  float a0 = 0.f, a1 = 0.f, a2 = 0.f, a3 = 0.f;
  float c0 = 0.f, c1 = 0.f, c2 = 0.f, c3 = 0.f;
  for (int kk = 0; kk < D_; kk += 4) {
    float w0 = wp[(size_t)kk * D_], w1 = wp[(size_t)(kk + 1) * D_];
    float w2 = wp[(size_t)(kk + 2) * D_], w3 = wp[(size_t)(kk + 3) * D_];
    float4 h0 = *(const float4*)(sAO + kk);
    float4 h1 = *(const float4*)(sAO + D_ + kk);
    a0 = fmaf(h0.x, w0, a0); a1 = fmaf(h0.y, w1, a1);
    a2 = fmaf(h0.z, w2, a2); a3 = fmaf(h0.w, w3, a3);
    c0 = fmaf(h1.x, w0, c0); c1 = fmaf(h1.y, w1, c1);
    c2 = fmaf(h1.z, w2, c2); c3 = fmaf(h1.w, w3, c3);
  }
  float bb = bo[tid];
  float v0 = x[(size_t)r0 * D_ + tid]       + bb + (a0 + a1) + (a2 + a3);
  float v1 = x[(size_t)(r0 + 1) * D_ + tid] + bb + (c0 + c1) + (c2 + c3);
  float s0 = v0, q0 = v0 * v0, s1 = v1, q1 = v1 * v1;
  #pragma unroll
  for (int off = 32; off >= 1; off >>= 1) {
    s0 += __shfl_xor(s0, off, 64); q0 += __shfl_xor(q0, off, 64);
    s1 += __shfl_xor(s1, off, 64); q1 += __shfl_xor(q1, off, 64);
  }
  if (lane == 0) {
    wred[0][wave] = s0; wred[1][wave] = q0;
    wred[2][wave] = s1; wred[3][wave] = q1;
  }
  __syncthreads();
  float S0 = wred[0][0] + wred[0][1] + wred[0][2] + wred[0][3];
  float Q0 = wred[1][0] + wred[1][1] + wred[1][2] + wred[1][3];
  float S1 = wred[2][0] + wred[2][1] + wred[2][2] + wred[2][3];
  float Q1 = wred[3][0] + wred[3][1] + wred[3][2] + wred[3][3];
  float m0 = S0 * (1.0f / D_), m1 = S1 * (1.0f / D_);
  float r0v = rsqrtf(Q0 * (1.0f / D_) - m0 * m0 + 1e-5f);
  float r1v = rsqrtf(Q1 * (1.0f / D_) - m1 * m1 + 1e-5f);
  float wv = lnw[tid], bv = lnb[tid];
  x[(size_t)r0 * D_ + tid]       = (v0 - m0) * r0v * wv + bv;
  x[(size_t)(r0 + 1) * D_ + tid] = (v1 - m1) * r1v * wv + bv;
}

// ---------------- gemm4t: C = A@W + bias (+resid), col-tile 32 x k-chunk 8 ----------------
// grid = (M/GR) * (Nc/32); dyn LDS = (GR*K + 1024) floats
__global__ void gemm4t_kernel(const float* __restrict__ A, const float* __restrict__ W,
                              const float* __restrict__ bias, const float* __restrict__ resid,
                              float* __restrict__ C, int K, int Nc) {
  int tiles = Nc >> 5;
  int bid = blockIdx.x;
  int tile = bid % tiles;
  int r0 = (bid / tiles) * GR;
  int tid = threadIdx.x;           // 256
  extern __shared__ __align__(16) float sA[];
  float* red = sA + GR * K;        // 1024 floats
  {
    int r = tid >> 6, lane = tid & 63;
    for (int kk = lane; kk < (K >> 2); kk += 64)
      ((float4*)(sA + r * K))[kk] = ((const float4*)(A + (size_t)(r0 + r) * K))[kk];
  }
  __syncthreads();
  int kc = tid >> 5, c = tid & 31;     // 8 k-chunks x 32 cols
  int KC = K >> 3;
  const float* wp = W + (size_t)(kc * KC) * Nc + tile * 32 + c;
  const float* s0 = sA + kc * KC;
  float a0 = 0.f, a1 = 0.f, a2 = 0.f, a3 = 0.f;
  for (int kk = 0; kk < KC; kk += 4) {
    float w0 = wp[(size_t)kk * Nc], w1 = wp[(size_t)(kk + 1) * Nc];
    float w2 = wp[(size_t)(kk + 2) * Nc], w3 = wp[(size_t)(kk + 3) * Nc];
    float4 h0 = *(const float4*)(s0 + 0 * K + kk);
    float4 h1 = *(const float4*)(s0 + 1 * K + kk);
    float4 h2 = *(const float4*)(s0 + 2 * K + kk);
    float4 h3 = *(const float4*)(s0 + 3 * K + kk);
    a0 = fmaf(h0.x, w0, fmaf(h0.y, w1, fmaf(h0.z, w2, fmaf(h0.w, w3, a0))));
    a1 = fmaf(h1.x, w0, fmaf(h1.y, w1, fmaf(h1.z, w2, fmaf(h1.w, w3, a1))));
    a2 = fmaf(h2.x, w0, fmaf(h2.y, w1, fmaf(h2.z, w2, fmaf(h2.w, w3, a2))));
    a3 = fmaf(h3.x, w0, fmaf(h3.y, w1, fmaf(h3.z, w2, fmaf(h3.w, w3, a3))));
  }
  red[(kc * 4 + 0) * 32 + c] = a0;
  red[(kc * 4 + 1) * 32 + c] = a1;
  red[(kc * 4 + 2) * 32 + c] = a2;
  red[(kc * 4 + 3) * 32 + c] = a3;
  __syncthreads();
  if (tid < GR * 32) {
    int r = tid >> 5, cc = tid & 31;
    float s = 0.f;
    #pragma unroll
    for (int k8 = 0; k8 < 8; k8++) s += red[(k8 * 4 + r) * 32 + cc];
    int col = tile * 32 + cc;
    if (bias)  s += bias[col];
    if (resid) s += resid[(size_t)(r0 + r) * Nc + col];
    C[(size_t)(r0 + r) * Nc + col] = s;
  }
}

// ---------------- ff1: f = gelu(LN(x)@W1+b1); 8 col-tiles x 2 k-chunks ----------------
// grid = (M/GR) * 8 = 1536
__global__ void ff1_kernel(const float* __restrict__ x,
                           const float* __restrict__ lnw, const float* __restrict__ lnb,
                           const float* __restrict__ W1, const float* __restrict__ b1,
                           float* __restrict__ f) {
  int bid = blockIdx.x;
  int tile = bid & 7;              // 128 cols each
  int r0 = (bid >> 3) * GR;
  int tid = threadIdx.x;
  __shared__ __align__(16) float sA[GR * D_];
  __shared__ float red[2 * GR * 128];
  {
    int r = tid >> 6, lane = tid & 63;
    float4 v = ((const float4*)(x + (size_t)(r0 + r) * D_))[lane];
    float s = v.x + v.y + v.z + v.w;
    float s2 = v.x * v.x + v.y * v.y + v.z * v.z + v.w * v.w;
    #pragma unroll
    for (int off = 32; off >= 1; off >>= 1) {
      s  += __shfl_xor(s, off, 64);
      s2 += __shfl_xor(s2, off, 64);
    }
    float mean = s * (1.0f / D_);
    float var = s2 * (1.0f / D_) - mean * mean;
    float rin = rsqrtf(var + 1e-5f);
    float4 w4 = ((const float4*)lnw)[lane];
    float4 b4 = ((const float4*)lnb)[lane];
    float4 nv;
    nv.x = (v.x - mean) * rin * w4.x + b4.x;
    nv.y = (v.y - mean) * rin * w4.y + b4.y;
    nv.z = (v.z - mean) * rin * w4.z + b4.z;
    nv.w = (v.w - mean) * rin * w4.w + b4.w;
    ((float4*)(sA + r * D_))[lane] = nv;
  }
  __syncthreads();
  int kc = tid >> 7, c = tid & 127;   // 2 k-chunks x 128 cols
  int col = tile * 128 + c;
  const float* wp = W1 + (size_t)(kc * 128) * 1024 + col;
  const float* s0 = sA + kc * 128;
  float a0 = 0.f, a1 = 0.f, a2 = 0.f, a3 = 0.f;
  for (int kk = 0; kk < 128; kk += 4) {
    float w0 = wp[(size_t)kk * 1024], w1 = wp[(size_t)(kk + 1) * 1024];
    float w2 = wp[(size_t)(kk + 2) * 1024], w3 = wp[(size_t)(kk + 3) * 1024];
    float4 h0 = *(const float4*)(s0 + 0 * D_ + kk);
    float4 h1 = *(const float4*)(s0 + 1 * D_ + kk);
    float4 h2 = *(const float4*)(s0 + 2 * D_ + kk);
    float4 h3 = *(const float4*)(s0 + 3 * D_ + kk);
    a0 = fmaf(h0.x, w0, fmaf(h0.y, w1, fmaf(h0.z, w2, fmaf(h0.w, w3, a0))));
    a1 = fmaf(h1.x, w0, fmaf(h1.y, w1, fmaf(h1.z, w2, fmaf(h1.w, w3, a1))));
    a2 = fmaf(h2.x, w0, fmaf(h2.y, w1, fmaf(h2.z, w2, fmaf(h2.w, w3, a2))));
    a3 = fmaf(h3.x, w0, fmaf(h3.y, w1, fmaf(h3.z, w2, fmaf(h3.w, w3, a3))));
  }
  red[(kc * 4 + 0) * 128 + c] = a0;
  red[(kc * 4 + 1) * 128 + c] = a1;
  red[(kc * 4 + 2) * 128 + c] = a2;
  red[(kc * 4 + 3) * 128 + c] = a3;
  __syncthreads();
  int rA = tid >> 7;                 // 0..1 -> rows rA, rA+2
  #pragma unroll
  for (int p = 0; p < 2; p++) {
    int r = rA + p * 2;
    float s = red[(0 * 4 + r) * 128 + c] + red[(1 * 4 + r) * 128 + c] + b1[col];
    s = 0.5f * s * (1.0f + erff(s * 0.7071067811865475f));
    f[(size_t)(r0 + r) * 1024 + col] = s;
  }
}

// ---------------- attention: i-tiled (IT=8), K/V staged in LDS once per block ----------------
// grid = B*H*(N/IT) = 768, 256 threads
__global__ void attn_kernel(const float* __restrict__ Q, const float* __restrict__ KT,
                            const float* __restrict__ V,
                            const float* __restrict__ tx, const float* __restrict__ ty,
                            const float* __restrict__ tz, float* __restrict__ AO) {
  const int TILES = N_ / IT;       // 48
  int bid = blockIdx.x;
  int it = bid % TILES;
  int h  = (bid / TILES) % H_;
  int b  = bid / (TILES * H_);
  int i0 = it * IT;
  int tid = threadIdx.x;
  int wave = tid >> 6, lane = tid & 63;

  __shared__ __align__(16) float sQ[IT * DH_];
  __shared__ __align__(16) float sK[DH_ * 64];
  __shared__ __align__(16) float sV[64 * DH_];
  __shared__ float sS[IT][N_];
  __shared__ float sti[3][IT];
  __shared__ float sinv[IT];

  {
    int ii = tid >> 5, d = tid & 31;
    sQ[ii * DH_ + d] = Q[((size_t)(b * N_ + i0 + ii)) * D_ + h * DH_ + d];
  }
  if (tid < IT) {
    sti[0][tid] = tx[b * N_ + i0 + tid];
    sti[1][tid] = ty[b * N_ + i0 + tid];
    sti[2][tid] = tz[b * N_ + i0 + tid];
  }
  const float* ktb = KT + (size_t)(b * H_ + h) * DH_ * N_;
  const float* vb  = V + (size_t)b * N_ * D_ + h * DH_;
  const float* txb = tx + b * N_;
  const float* tyb = ty + b * N_;
  const float* tzb = tz + b * N_;
  __syncthreads();

  for (int jc = 0; jc < N_; jc += 64) {
    for (int idx = tid; idx < DH_ * 64; idx += 256) {
      int d = idx >> 6, jj = idx & 63;
      sK[d * 64 + jj] = ktb[(size_t)d * N_ + jc + jj];
    }
    __syncthreads();
    int jj = lane;
    float tjx = txb[jc + jj], tjy = tyb[jc + jj], tjz = tzb[jc + jj];
    const float* q0 = sQ + (wave * 2 + 0) * DH_;
    const float* q1 = sQ + (wave * 2 + 1) * DH_;
    float a0 = 0.f, a1 = 0.f;
    #pragma unroll 8
    for (int d = 0; d < DH_; d++) {
      float kv = sK[d * 64 + jj];
      a0 = fmaf(q0[d], kv, a0);
      a1 = fmaf(q1[d], kv, a1);
    }
    #pragma unroll
    for (int s = 0; s < 2; s++) {
      int ii = wave * 2 + s;
      float a = (s == 0) ? a0 : a1;
      float dx = sti[0][ii] - tjx;
      float dy = sti[1][ii] - tjy;
      float dz = sti[2][ii] - tjz;
      sS[ii][jc + jj] = a * 0.17677669529663689f - (dx * dx + dy * dy + dz * dz);
    }
    __syncthreads();
  }

  #pragma unroll
  for (int s = 0; s < 2; s++) {
    int ii = wave * 2 + s;
    float vrow[6];
    float m = -1e30f;
    #pragma unroll
    for (int t = 0; t < 6; t++) { vrow[t] = sS[ii][t * 64 + lane]; m = fmaxf(m, vrow[t]); }
    #pragma unroll
    for (int off = 32; off >= 1; off >>= 1) m = fmaxf(m, __shfl_xor(m, off, 64));
    float ps = 0.f;
    #pragma unroll
    for (int t = 0; t < 6; t++) {
      float e = expf(vrow[t] - m);
      sS[ii][t * 64 + lane] = e;
      ps += e;
    }
    #pragma unroll
    for (int off = 32; off >= 1; off >>= 1) ps += __shfl_xor(ps, off, 64);
    if (lane == 0) sinv[ii] = 1.0f / ps;
  }
  __syncthreads();

  int ii = tid >> 5, dd = tid & 31;
  float o0 = 0.f, o1 = 0.f;
  for (int jc = 0; jc < N_; jc += 64) {
    for (int idx = tid; idx < 64 * DH_; idx += 256) {
      int jj = idx >> 5, d = idx & 31;
      sV[jj * DH_ + d] = vb[(size_t)(jc + jj) * D_ + d];
    }
    __syncthreads();
    #pragma unroll 8
    for (int jj = 0; jj < 64; jj += 2) {
      o0 = fmaf(sS[ii][jc + jj],     sV[jj * DH_ + dd],       o0);
      o1 = fmaf(sS[ii][jc + jj + 1], sV[(jj + 1) * DH_ + dd], o1);
    }
    __syncthreads();
  }
  AO[((size_t)(b * N_ + i0 + ii)) * D_ + h * DH_ + dd] = (o0 + o1) * sinv[ii];
}

// ---------------- fused pair LN-mean + head ----------------
// grid = M, 256 threads
__global__ void pair_head_kernel(const float* __restrict__ proj, const float* __restrict__ relpos,
                                 const float* __restrict__ mp, const float* __restrict__ mr,
                                 const float* __restrict__ lnw, const float* __restrict__ lnb,
                                 const float* __restrict__ x,
                                 const float* __restrict__ Wf1, const float* __restrict__ bWf1,
                                 const float* __restrict__ Wf2, const float* __restrict__ bWf2,
                                 float* __restrict__ frames, float* __restrict__ tx,
                                 float* __restrict__ ty, float* __restrict__ tz) {
  int row = blockIdx.x;            // b*N + i
  int b = row / N_;
  int i = row % N_;
  int tid = threadIdx.x;           // 256 = 4 waves
  int lane = tid & 63;
  int wave = tid >> 6;
  __shared__ float red[4][PD_];
  __shared__ float sfeat[320];
  __shared__ float fred[2][128];
  __shared__ float sg[128];
  __shared__ float sraw[9];

  float vpi = proj[row * PD_ + lane];
  float mpi = mp[row];
  const float* pb  = proj + (size_t)b * N_ * PD_;
  const float* mpb = mp + b * N_;
  float acc = 0.0f;
  for (int j = wave * 2; j < N_; j += 8) {
    int ja = j, jb = j + 1;
    int ra = ja - i; ra = ra < -64 ? -64 : (ra > 64 ? 64 : ra); ra += 64;
    int rb = jb - i; rb = rb < -64 ? -64 : (rb > 64 ? 64 : rb); rb += 64;
    float va = vpi + pb[ja * PD_ + lane] + relpos[ra * PD_ + lane];
    float vb = vpi + pb[jb * PD_ + lane] + relpos[rb * PD_ + lane];
    float da = va - (mpi + mpb[ja] + mr[ra]);
    float db = vb - (mpi + mpb[jb] + mr[rb]);
    float s2a = da * da, s2b = db * db;
    #pragma unroll
    for (int off = 32; off >= 1; off >>= 1) {
      s2a += __shfl_xor(s2a, off, 64);
      s2b += __shfl_xor(s2b, off, 64);
    }
    float rinva = rsqrtf(s2a * (1.0f / PD_) + 1e-5f);
    float rinvb = rsqrtf(s2b * (1.0f / PD_) + 1e-5f);
    acc += da * rinva + db * rinvb;
  }
  red[wave][lane] = acc;
  if (tid < D_) sfeat[tid] = x[(size_t)row * D_ + tid];
  __syncthreads();
  if (wave == 0) {
    float s = red[0][lane] + red[1][lane] + red[2][lane] + red[3][lane];
    sfeat[D_ + lane] = lnb[lane] + s * lnw[lane] * (1.0f / N_);
  }
  __syncthreads();

  int kc = tid >> 7, c = tid & 127;
  int koff = kc * 160;
  const float* wp = Wf1 + (size_t)koff * 128 + c;
  const float* s0 = sfeat + koff;
  float a0 = 0.f, a1 = 0.f, a2 = 0.f, a3 = 0.f;
  for (int kk = 0; kk < 160; kk += 4) {
    a0 = fmaf(s0[kk],     wp[(size_t)kk * 128],       a0);
    a1 = fmaf(s0[kk + 1], wp[(size_t)(kk + 1) * 128], a1);
    a2 = fmaf(s0[kk + 2], wp[(size_t)(kk + 2) * 128], a2);
    a3 = fmaf(s0[kk + 3], wp[(size_t)(kk + 3) * 128], a3);
  }
  fred[kc][c] = (a0 + a1) + (a2 + a3);
  __syncthreads();
  if (tid < 128) {
    float g = fred[0][tid] + fred[1][tid] + bWf1[tid];
    sg[tid] = g / (1.0f + expf(-g));
  }
  __syncthreads();

  if (tid < 9) {
    float b0 = 0.f, b1v = 0.f;
    for (int kk = 0; kk < 128; kk += 2) {
      b0  = fmaf(sg[kk],     Wf2[(kk)     * 9 + tid], b0);
      b1v = fmaf(sg[kk + 1], Wf2[(kk + 1) * 9 + tid], b1v);
    }
    sraw[tid] = bWf2[tid] + b0 + b1v;
  }
  __syncthreads();
  if (tid == 0) {
    float a1x = sraw[0], a1y = sraw[1], a1z = sraw[2];
    float a2x = sraw[3], a2y = sraw[4], a2z = sraw[5];
    float n1 = sqrtf(a1x * a1x + a1y * a1y + a1z * a1z + 1e-8f);
    float b1x = a1x / n1, b1y = a1y / n1, b1z = a1z / n1;
    float dp = b1x * a2x + b1y * a2y + b1z * a2z;
    float px = a2x - dp * b1x, py = a2y - dp * b1y, pz = a2z - dp * b1z;
    float n2 = sqrtf(px * px + py * py + pz * pz + 1e-8f);
    float b2x = px / n2, b2y = py / n2, b2z = pz / n2;
    float b3x = b1y * b2z - b1z * b2y;
    float b3y = b1z * b2x - b1x * b2z;
    float b3z = b1x * b2y - b1y * b2x;
    float* f = frames + row * 16;
    f[0]  = b1x; f[1]  = b1y; f[2]  = b1z; f[3]  = sraw[6];
    f[4]  = b2x; f[5]  = b2y; f[6]  = b2z; f[7]  = sraw[7];
    f[8]  = b3x; f[9]  = b3y; f[10] = b3z; f[11] = sraw[8];
    f[12] = 0.0f; f[13] = 0.0f; f[14] = 0.0f; f[15] = 1.0f;
    tx[row] = sraw[6];
    ty[row] = sraw[7];
    tz[row] = sraw[8];
  }
}

// ---------------- output ----------------
__global__ void write_out_kernel(const float* __restrict__ frames, const float* __restrict__ x,
                                 float* __restrict__ out) {
  int i = blockIdx.x * 256 + threadIdx.x;
  const int nf = B_ * N_ * 16;
  const int total = nf + B_ * N_ * D_;
  if (i < nf) out[i] = frames[i];
  else if (i < total) out[i] = x[i - nf];
}

extern "C" void kernel_launch(void* const* d_in, const int* in_sizes, int n_in,
                              void* d_out, int out_size, void* d_ws, size_t ws_size,
                              hipStream_t stream) {
  const int*   tokens    = (const int*)  d_in[0];
  const float* tok_emb   = (const float*)d_in[1];
  const float* emb_ln_w  = (const float*)d_in[2];
  const float* emb_ln_b  = (const float*)d_in[3];
  const float* Wq        = (const float*)d_in[4];
  const float* Wk        = (const float*)d_in[5];
  const float* Wv        = (const float*)d_in[6];
  const float* Wo        = (const float*)d_in[7];
  const float* bo        = (const float*)d_in[8];
  const float* attn_ln_w = (const float*)d_in[9];
  const float* attn_ln_b = (const float*)d_in[10];
  const float* ff_ln_w   = (const float*)d_in[11];
  const float* ff_ln_b   = (const float*)d_in[12];
  const float* W1        = (const float*)d_in[13];
  const float* b1        = (const float*)d_in[14];
  const float* W2        = (const float*)d_in[15];
  const float* b2        = (const float*)d_in[16];
  const float* Wop       = (const float*)d_in[17];
  const float* bop       = (const float*)d_in[18];
  const float* relpos    = (const float*)d_in[19];
  const float* pair_ln_w = (const float*)d_in[20];
  const float* pair_ln_b = (const float*)d_in[21];
  const float* Wf1       = (const float*)d_in[22];
  const float* bWf1      = (const float*)d_in[23];
  const float* Wf2       = (const float*)d_in[24];
  const float* bWf2      = (const float*)d_in[25];

  const int M = B_ * N_;           // 768
  const int XE = M * D_;           // 196608
  float* ws     = (float*)d_ws;
  float* frames = ws;                      // 12288
  float* proj   = frames + M * 16;         // 49152
  float* mp     = proj   + M * PD_;        // 768
  float* mr     = mp     + M;              // 129 (pad 192)
  float* tx     = mr     + 192;            // 768
  float* ty     = tx     + M;              // 768
  float* tz     = ty     + M;              // 768
  float* x      = tz     + M;              // XE
  float* q      = x  + XE;                 // XE
  float* kt     = q  + XE;                 // XE (K transposed [b,h,d,j])
  float* v      = kt + XE;                 // XE
  float* ao     = v  + XE;                 // XE
  float* f      = q;                       // alias: q..ao = 4*XE (ff intermediate)

  prologue_kernel<<<M, 256, 0, stream>>>(tokens, tok_emb, emb_ln_w, emb_ln_b, relpos,
                                         x, frames, tx, ty, tz, mr);
  qkv_kernel<<<(M / GR) * 12, 256, 0, stream>>>(x, Wq, Wk, Wv, q, kt, v);

  const size_t lds_ff2 = (GR * 1024 + 1024) * sizeof(float);   // 20 KB

  for (int l = 0; l < L_; l++) {
    attn_kernel<<<B_ * H_ * (N_ / IT), 256, 0, stream>>>(q, kt, v, tx, ty, tz, ao);
    wo_ln_kernel<<<M / 2, 256, 0, stream>>>(ao, Wo + (size_t)l * D_ * D_, bo + l * D_,
                                            attn_ln_w + l * D_, attn_ln_b + l * D_, x);
    ff1_kernel<<<(M / GR) * 8, 256, 0, stream>>>(x, ff_ln_w + l * D_, ff_ln_b + l * D_,
                                                 W1 + (size_t)l * D_ * 1024, b1 + l * 1024, f);
    gemm4t_kernel<<<(M / GR) * 8, 256, lds_ff2, stream>>>(
        f, W2 + (size_t)l * 1024 * D_, b2 + l * D_, x, x, 1024, D_);
    if (l < L_ - 1) {
      // proj(l) + qkv(l+1): both read only x, disjoint writes
      int lq = l + 1;
      proj_qkv_kernel<<<M + (M / GR) * 12, 256, 0, stream>>>(
          x, Wop, bop, proj, mp,
          Wq + (size_t)lq * D_ * D_, Wk + (size_t)lq * D_ * D_, Wv + (size_t)lq * D_ * D_,
          q, kt, v);
    } else {
      proj_qkv_kernel<<<M, 256, 0, stream>>>(x, Wop, bop, proj, mp, Wq, Wk, Wv, q, kt, v);
    }
    pair_head_kernel<<<M, 256, 0, stream>>>(proj, relpos, mp, mr, pair_ln_w, pair_ln_b,
                                            x, Wf1, bWf1, Wf2, bWf2, frames, tx, ty, tz);
  }

  const int total = B_ * N_ * 16 + B_ * N_ * D_;
  write_out_kernel<<<(total + 255) / 256, 256, 0, stream>>>(frames, x, (float*)d_out);
}

// Round 14
// 1022.315 us; speedup vs baseline: 1.1124x; 1.0537x over previous
//
#include <hip/hip_runtime.h>
#include <hip/hip_bf16.h>
#include <math.h>

#define B_  2
#define N_  384
#define D_  256
#define PD_ 64
#define L_  8
#define H_  8
#define DH_ 32
#define GR  4      // rows per GEMM block
#define IT  8      // attention i-tile
#define RT_ 132    // relcT row stride (129 padded)

// ---------------- prologue: embed+LN, frames/t init, centered relpos (+transpose) ----------------
// grid = M, 256 threads
__global__ void prologue_kernel(const int* __restrict__ tokens, const float* __restrict__ tok_emb,
                                const float* __restrict__ lnw, const float* __restrict__ lnb,
                                const float* __restrict__ relpos,
                                float* __restrict__ x, float* __restrict__ frames,
                                float* __restrict__ tx, float* __restrict__ ty,
                                float* __restrict__ tz,
                                float* __restrict__ relc, float* __restrict__ relcT) {
  int row = blockIdx.x;            // b*N + n
  int n = row % N_;
  int d = threadIdx.x;             // 0..255
  __shared__ float rbuf[256];
  __shared__ float smr;
  if (d < 16) frames[row * 16 + d] = (d == 0 || d == 5 || d == 10 || d == 15) ? 1.0f : 0.0f;
  if (d == 16) tx[row] = 0.0f;
  if (d == 17) ty[row] = 0.0f;
  if (d == 18) tz[row] = 0.0f;
  // rel row mean (blocks 0..128, wave 3)
  if (row < 129 && d >= 192) {
    int lane = d & 63;
    float s = relpos[row * PD_ + lane];
    #pragma unroll
    for (int off = 32; off >= 1; off >>= 1) s += __shfl_xor(s, off, 64);
    if (lane == 0) smr = s * (1.0f / PD_);
  }
  // embed + pos-enc + LN
  int tok = tokens[row];
  float val = tok_emb[tok * D_ + d];
  int i = d >> 1;
  float dv = expf((float)(2 * i) * (-logf(10000.0f) / (float)D_));
  float ang = (float)n * dv;
  val += (d & 1) ? cosf(ang) : sinf(ang);
  rbuf[d] = val; __syncthreads();          // smr visible after this
  for (int s = 128; s > 0; s >>= 1) { if (d < s) rbuf[d] += rbuf[d + s]; __syncthreads(); }
  float mean = rbuf[0] / D_;
  __syncthreads();
  rbuf[d] = val * val; __syncthreads();
  for (int s = 128; s > 0; s >>= 1) { if (d < s) rbuf[d] += rbuf[d + s]; __syncthreads(); }
  float var = rbuf[0] / D_ - mean * mean;
  float r = rsqrtf(var + 1e-5f);
  x[row * D_ + d] = (val - mean) * r * lnw[d] + lnb[d];
  // centered relpos + transpose
  if (row < 129 && d < PD_) {
    float cv = relpos[row * PD_ + d] - smr;
    relc[row * PD_ + d] = cv;
    relcT[d * RT_ + row] = cv;
  }
}

// ---------------- qkv unit (GR=4, k-chunk 4 x col-tile 64; K transposed) ----------------
__device__ __forceinline__ void qkv_unit(int bid, int tid, const float* __restrict__ x,
                                         const float* __restrict__ Wq, const float* __restrict__ Wk,
                                         const float* __restrict__ Wv,
                                         float* __restrict__ q, float* __restrict__ kt,
                                         float* __restrict__ v, float* sA) {
  int tile = bid & 3;
  int m = (bid >> 2) % 3;
  int r0 = (bid / 12) * GR;
  float* red = sA + GR * D_;       // 1024 floats
  {
    int r = tid >> 6, lane = tid & 63;
    ((float4*)(sA + r * D_))[lane] = ((const float4*)(x + (size_t)(r0 + r) * D_))[lane];
  }
  __syncthreads();
  const float* W = (m == 0) ? Wq : (m == 1) ? Wk : Wv;
  int kc = tid >> 6, c = tid & 63;
  const float* wp = W + (size_t)(kc * 64) * D_ + tile * 64 + c;
  const float* s0 = sA + kc * 64;
  float a0 = 0.f, a1 = 0.f, a2 = 0.f, a3 = 0.f;
  for (int kk = 0; kk < 64; kk += 4) {
    float w0 = wp[(size_t)kk * D_], w1 = wp[(size_t)(kk + 1) * D_];
    float w2 = wp[(size_t)(kk + 2) * D_], w3 = wp[(size_t)(kk + 3) * D_];
    float4 h0 = *(const float4*)(s0 + 0 * D_ + kk);
    float4 h1 = *(const float4*)(s0 + 1 * D_ + kk);
    float4 h2 = *(const float4*)(s0 + 2 * D_ + kk);
    float4 h3 = *(const float4*)(s0 + 3 * D_ + kk);
    a0 = fmaf(h0.x, w0, fmaf(h0.y, w1, fmaf(h0.z, w2, fmaf(h0.w, w3, a0))));
    a1 = fmaf(h1.x, w0, fmaf(h1.y, w1, fmaf(h1.z, w2, fmaf(h1.w, w3, a1))));
    a2 = fmaf(h2.x, w0, fmaf(h2.y, w1, fmaf(h2.z, w2, fmaf(h2.w, w3, a2))));
    a3 = fmaf(h3.x, w0, fmaf(h3.y, w1, fmaf(h3.z, w2, fmaf(h3.w, w3, a3))));
  }
  red[(kc * 4 + 0) * 64 + c] = a0;
  red[(kc * 4 + 1) * 64 + c] = a1;
  red[(kc * 4 + 2) * 64 + c] = a2;
  red[(kc * 4 + 3) * 64 + c] = a3;
  __syncthreads();
  int r = tid >> 6;
  float s = red[(0 * 4 + r) * 64 + c] + red[(1 * 4 + r) * 64 + c]
          + red[(2 * 4 + r) * 64 + c] + red[(3 * 4 + r) * 64 + c];
  int col = tile * 64 + c;
  int row = r0 + r;
  if (m == 1) {
    int b = row / N_, j = row % N_;
    int hh = col >> 5, dd = col & 31;
    kt[((size_t)(b * H_ + hh) * DH_ + dd) * N_ + j] = s;
  } else {
    float* O = (m == 0) ? q : v;
    O[(size_t)row * D_ + col] = s;
  }
}

// ---------------- proj unit: centered relu(x@Wop+bop) -> projc (+transposed) ----------------
__device__ __forceinline__ void proj_unit(int row, int tid, const float* __restrict__ x,
                                          const float* __restrict__ Wop, const float* __restrict__ bop,
                                          float* __restrict__ projc, float* __restrict__ projcT,
                                          float* smem) {
  float* sA  = smem;               // 256
  float* red = smem + 256;         // 256
  if (tid < 64) ((float4*)sA)[tid] = ((const float4*)(x + (size_t)row * D_))[tid];
  __syncthreads();
  int kc = tid >> 6, c = tid & 63;
  const float* wp = Wop + (kc * 64) * PD_ + c;
  const float* s0 = sA + kc * 64;
  float a0 = 0.f, a1 = 0.f, a2 = 0.f, a3 = 0.f;
  for (int kk = 0; kk < 64; kk += 4) {
    a0 = fmaf(s0[kk],     wp[(kk)     * PD_], a0);
    a1 = fmaf(s0[kk + 1], wp[(kk + 1) * PD_], a1);
    a2 = fmaf(s0[kk + 2], wp[(kk + 2) * PD_], a2);
    a3 = fmaf(s0[kk + 3], wp[(kk + 3) * PD_], a3);
  }
  red[kc * 64 + c] = (a0 + a1) + (a2 + a3);
  __syncthreads();
  if (tid < 64) {
    float acc = fmaxf(bop[tid] + red[tid] + red[64 + tid] + red[128 + tid] + red[192 + tid], 0.0f);
    float s = acc;
    #pragma unroll
    for (int off = 32; off >= 1; off >>= 1) s += __shfl_xor(s, off, 64);
    float cv = acc - s * (1.0f / PD_);
    projc[row * PD_ + tid] = cv;
    projcT[(size_t)tid * (B_ * N_) + row] = cv;
  }
}

// ---------------- standalone qkv (layer 0) ----------------
__global__ void qkv_kernel(const float* __restrict__ x, const float* __restrict__ Wq,
                           const float* __restrict__ Wk, const float* __restrict__ Wv,
                           float* __restrict__ q, float* __restrict__ kt, float* __restrict__ v) {
  __shared__ __align__(16) float smem[2048];
  qkv_unit(blockIdx.x, threadIdx.x, x, Wq, Wk, Wv, q, kt, v, smem);
}

// ---------------- combined proj(l) + qkv(l+1): both read only x ----------------
__global__ void proj_qkv_kernel(const float* __restrict__ x,
                                const float* __restrict__ Wop, const float* __restrict__ bop,
                                float* __restrict__ projc, float* __restrict__ projcT,
                                const float* __restrict__ Wq, const float* __restrict__ Wk,
                                const float* __restrict__ Wv,
                                float* __restrict__ q, float* __restrict__ kt,
                                float* __restrict__ v) {
  __shared__ __align__(16) float smem[2048];
  int bid = blockIdx.x, tid = threadIdx.x;
  if (bid < B_ * N_) proj_unit(bid, tid, x, Wop, bop, projc, projcT, smem);
  else               qkv_unit(bid - B_ * N_, tid, x, Wq, Wk, Wv, q, kt, v, smem);
}

// ---------------- fused Wo-GEMM + residual + LN: x = LN(x + ao@Wo + bo) ----------------
// grid = M/2 = 384, 256 threads (2 rows/block)
__global__ void wo_ln_kernel(const float* __restrict__ ao, const float* __restrict__ Wo,
                             const float* __restrict__ bo,
                             const float* __restrict__ lnw, const float* __restrict__ lnb,
                             float* __restrict__ x) {
  int r0 = blockIdx.x * 2;
  int tid = threadIdx.x;           // 256
  int wave = tid >> 6, lane = tid & 63;
  __shared__ __align__(16) float sAO[2 * D_];
  __shared__ float wred[4][4];
  if (tid < 128) ((float4*)sAO)[tid] = ((const float4*)(ao + (size_t)r0 * D_))[tid];
  __syncthreads();
  const float* wp = Wo + tid;      // col = tid
  float a0 = 0.f, a1 = 0.f, a2 = 0.f, a3 = 0.f;
  float c0 = 0.f, c1 = 0.f, c2 = 0.f, c3 = 0.f;
  for (int kk = 0; kk < D_; kk += 4) {
    float w0 = wp[(size_t)kk * D_], w1 = wp[(size_t)(kk + 1) * D_];
    float w2 = wp[(size_t)(kk + 2) * D_], w3 = wp[(size_t)(kk + 3) * D_];
    float4 h0 = *(const float4*)(sAO + kk);
    float4 h1 = *(const float4*)(sAO + D_ + kk);
    a0 = fmaf(h0.x, w0, a0); a1 = fmaf(h0.y, w1, a1);
    a2 = fmaf(h0.z, w2, a2); a3 = fmaf(h0.w, w3, a3);
    c0 = fmaf(h1.x, w0, c0); c1 = fmaf(h1.y, w1, c1);
    c2 = fmaf(h1.z, w2, c2); c3 = fmaf(h1.w, w3, c3);
  }
  float bb = bo[tid];
  float v0 = x[(size_t)r0 * D_ + tid]       + bb + (a0 + a1) + (a2 + a3);
  float v1 = x[(size_t)(r0 + 1) * D_ + tid] + bb + (c0 + c1) + (c2 + c3);
  float s0 = v0, q0 = v0 * v0, s1 = v1, q1 = v1 * v1;
  #pragma unroll
  for (int off = 32; off >= 1; off >>= 1) {
    s0 += __shfl_xor(s0, off, 64); q0 += __shfl_xor(q0, off, 64);
    s1 += __shfl_xor(s1, off, 64); q1 += __shfl_xor(q1, off, 64);
  }
  if (lane == 0) {
    wred[0][wave] = s0; wred[1][wave] = q0;
    wred[2][wave] = s1; wred[3][wave] = q1;
  }
  __syncthreads();
  float S0 = wred[0][0] + wred[0][1] + wred[0][2] + wred[0][3];
  float Q0 = wred[1][0] + wred[1][1] + wred[1][2] + wred[1][3];
  float S1 = wred[2][0] + wred[2][1] + wred[2][2] + wred[2][3];
  float Q1 = wred[3][0] + wred[3][1] + wred[3][2] + wred[3][3];
  float m0 = S0 * (1.0f / D_), m1 = S1 * (1.0f / D_);
  float r0v = rsqrtf(Q0 * (1.0f / D_) - m0 * m0 + 1e-5f);
  float r1v = rsqrtf(Q1 * (1.0f / D_) - m1 * m1 + 1e-5f);
  float wv = lnw[tid], bv = lnb[tid];
  x[(size_t)r0 * D_ + tid]       = (v0 - m0) * r0v * wv + bv;
  x[(size_t)(r0 + 1) * D_ + tid] = (v1 - m1) * r1v * wv + bv;
}

// ---------------- gemm4t: C = A@W + bias (+resid), col-tile 32 x k-chunk 8 ----------------
__global__ void gemm4t_kernel(const float* __restrict__ A, const float* __restrict__ W,
                              const float* __restrict__ bias, const float* __restrict__ resid,
                              float* __restrict__ C, int K, int Nc) {
  int tiles = Nc >> 5;
  int bid = blockIdx.x;
  int tile = bid % tiles;
  int r0 = (bid / tiles) * GR;
  int tid = threadIdx.x;           // 256
  extern __shared__ __align__(16) float sA[];
  float* red = sA + GR * K;        // 1024 floats
  {
    int r = tid >> 6, lane = tid & 63;
    for (int kk = lane; kk < (K >> 2); kk += 64)
      ((float4*)(sA + r * K))[kk] = ((const float4*)(A + (size_t)(r0 + r) * K))[kk];
  }
  __syncthreads();
  int kc = tid >> 5, c = tid & 31;     // 8 k-chunks x 32 cols
  int KC = K >> 3;
  const float* wp = W + (size_t)(kc * KC) * Nc + tile * 32 + c;
  const float* s0 = sA + kc * KC;
  float a0 = 0.f, a1 = 0.f, a2 = 0.f, a3 = 0.f;
  for (int kk = 0; kk < KC; kk += 4) {
    float w0 = wp[(size_t)kk * Nc], w1 = wp[(size_t)(kk + 1) * Nc];
    float w2 = wp[(size_t)(kk + 2) * Nc], w3 = wp[(size_t)(kk + 3) * Nc];
    float4 h0 = *(const float4*)(s0 + 0 * K + kk);
    float4 h1 = *(const float4*)(s0 + 1 * K + kk);
    float4 h2 = *(const float4*)(s0 + 2 * K + kk);
    float4 h3 = *(const float4*)(s0 + 3 * K + kk);
    a0 = fmaf(h0.x, w0, fmaf(h0.y, w1, fmaf(h0.z, w2, fmaf(h0.w, w3, a0))));
    a1 = fmaf(h1.x, w0, fmaf(h1.y, w1, fmaf(h1.z, w2, fmaf(h1.w, w3, a1))));
    a2 = fmaf(h2.x, w0, fmaf(h2.y, w1, fmaf(h2.z, w2, fmaf(h2.w, w3, a2))));
    a3 = fmaf(h3.x, w0, fmaf(h3.y, w1, fmaf(h3.z, w2, fmaf(h3.w, w3, a3))));
  }
  red[(kc * 4 + 0) * 32 + c] = a0;
  red[(kc * 4 + 1) * 32 + c] = a1;
  red[(kc * 4 + 2) * 32 + c] = a2;
  red[(kc * 4 + 3) * 32 + c] = a3;
  __syncthreads();
  if (tid < GR * 32) {
    int r = tid >> 5, cc = tid & 31;
    float s = 0.f;
    #pragma unroll
    for (int k8 = 0; k8 < 8; k8++) s += red[(k8 * 4 + r) * 32 + cc];
    int col = tile * 32 + cc;
    if (bias)  s += bias[col];
    if (resid) s += resid[(size_t)(r0 + r) * Nc + col];
    C[(size_t)(r0 + r) * Nc + col] = s;
  }
}

// ---------------- ff1: f = gelu(LN(x)@W1+b1); 8 col-tiles x 2 k-chunks ----------------
__global__ void ff1_kernel(const float* __restrict__ x,
                           const float* __restrict__ lnw, const float* __restrict__ lnb,
                           const float* __restrict__ W1, const float* __restrict__ b1,
                           float* __restrict__ f) {
  int bid = blockIdx.x;
  int tile = bid & 7;              // 128 cols each
  int r0 = (bid >> 3) * GR;
  int tid = threadIdx.x;
  __shared__ __align__(16) float sA[GR * D_];
  __shared__ float red[2 * GR * 128];
  {
    int r = tid >> 6, lane = tid & 63;
    float4 v = ((const float4*)(x + (size_t)(r0 + r) * D_))[lane];
    float s = v.x + v.y + v.z + v.w;
    float s2 = v.x * v.x + v.y * v.y + v.z * v.z + v.w * v.w;
    #pragma unroll
    for (int off = 32; off >= 1; off >>= 1) {
      s  += __shfl_xor(s, off, 64);
      s2 += __shfl_xor(s2, off, 64);
    }
    float mean = s * (1.0f / D_);
    float var = s2 * (1.0f / D_) - mean * mean;
    float rin = rsqrtf(var + 1e-5f);
    float4 w4 = ((const float4*)lnw)[lane];
    float4 b4 = ((const float4*)lnb)[lane];
    float4 nv;
    nv.x = (v.x - mean) * rin * w4.x + b4.x;
    nv.y = (v.y - mean) * rin * w4.y + b4.y;
    nv.z = (v.z - mean) * rin * w4.z + b4.z;
    nv.w = (v.w - mean) * rin * w4.w + b4.w;
    ((float4*)(sA + r * D_))[lane] = nv;
  }
  __syncthreads();
  int kc = tid >> 7, c = tid & 127;   // 2 k-chunks x 128 cols
  int col = tile * 128 + c;
  const float* wp = W1 + (size_t)(kc * 128) * 1024 + col;
  const float* s0 = sA + kc * 128;
  float a0 = 0.f, a1 = 0.f, a2 = 0.f, a3 = 0.f;
  for (int kk = 0; kk < 128; kk += 4) {
    float w0 = wp[(size_t)kk * 1024], w1 = wp[(size_t)(kk + 1) * 1024];
    float w2 = wp[(size_t)(kk + 2) * 1024], w3 = wp[(size_t)(kk + 3) * 1024];
    float4 h0 = *(const float4*)(s0 + 0 * D_ + kk);
    float4 h1 = *(const float4*)(s0 + 1 * D_ + kk);
    float4 h2 = *(const float4*)(s0 + 2 * D_ + kk);
    float4 h3 = *(const float4*)(s0 + 3 * D_ + kk);
    a0 = fmaf(h0.x, w0, fmaf(h0.y, w1, fmaf(h0.z, w2, fmaf(h0.w, w3, a0))));
    a1 = fmaf(h1.x, w0, fmaf(h1.y, w1, fmaf(h1.z, w2, fmaf(h1.w, w3, a1))));
    a2 = fmaf(h2.x, w0, fmaf(h2.y, w1, fmaf(h2.z, w2, fmaf(h2.w, w3, a2))));
    a3 = fmaf(h3.x, w0, fmaf(h3.y, w1, fmaf(h3.z, w2, fmaf(h3.w, w3, a3))));
  }
  red[(kc * 4 + 0) * 128 + c] = a0;
  red[(kc * 4 + 1) * 128 + c] = a1;
  red[(kc * 4 + 2) * 128 + c] = a2;
  red[(kc * 4 + 3) * 128 + c] = a3;
  __syncthreads();
  int rA = tid >> 7;                 // 0..1 -> rows rA, rA+2
  #pragma unroll
  for (int p = 0; p < 2; p++) {
    int r = rA + p * 2;
    float s = red[(0 * 4 + r) * 128 + c] + red[(1 * 4 + r) * 128 + c] + b1[col];
    s = 0.5f * s * (1.0f + erff(s * 0.7071067811865475f));
    f[(size_t)(r0 + r) * 1024 + col] = s;
  }
}

// ---------------- attention: i-tiled (IT=8), K/V staged in LDS once per block ----------------
// grid = B*H*(N/IT) = 768, 256 threads
__global__ void attn_kernel(const float* __restrict__ Q, const float* __restrict__ KT,
                            const float* __restrict__ V,
                            const float* __restrict__ tx, const float* __restrict__ ty,
                            const float* __restrict__ tz, float* __restrict__ AO) {
  const int TILES = N_ / IT;       // 48
  int bid = blockIdx.x;
  int it = bid % TILES;
  int h  = (bid / TILES) % H_;
  int b  = bid / (TILES * H_);
  int i0 = it * IT;
  int tid = threadIdx.x;
  int wave = tid >> 6, lane = tid & 63;

  __shared__ __align__(16) float sQ[IT * DH_];
  __shared__ __align__(16) float sK[DH_ * 64];
  __shared__ __align__(16) float sV[64 * DH_];
  __shared__ float sS[IT][N_];
  __shared__ float sti[3][IT];
  __shared__ float sinv[IT];

  {
    int ii = tid >> 5, d = tid & 31;
    sQ[ii * DH_ + d] = Q[((size_t)(b * N_ + i0 + ii)) * D_ + h * DH_ + d];
  }
  if (tid < IT) {
    sti[0][tid] = tx[b * N_ + i0 + tid];
    sti[1][tid] = ty[b * N_ + i0 + tid];
    sti[2][tid] = tz[b * N_ + i0 + tid];
  }
  const float* ktb = KT + (size_t)(b * H_ + h) * DH_ * N_;
  const float* vb  = V + (size_t)b * N_ * D_ + h * DH_;
  const float* txb = tx + b * N_;
  const float* tyb = ty + b * N_;
  const float* tzb = tz + b * N_;
  __syncthreads();

  for (int jc = 0; jc < N_; jc += 64) {
    for (int idx = tid; idx < DH_ * 64; idx += 256) {
      int d = idx >> 6, jj = idx & 63;
      sK[d * 64 + jj] = ktb[(size_t)d * N_ + jc + jj];
    }
    __syncthreads();
    int jj = lane;
    float tjx = txb[jc + jj], tjy = tyb[jc + jj], tjz = tzb[jc + jj];
    const float* q0 = sQ + (wave * 2 + 0) * DH_;
    const float* q1 = sQ + (wave * 2 + 1) * DH_;
    float a0 = 0.f, a1 = 0.f;
    #pragma unroll 8
    for (int d = 0; d < DH_; d++) {
      float kv = sK[d * 64 + jj];
      a0 = fmaf(q0[d], kv, a0);
      a1 = fmaf(q1[d], kv, a1);
    }
    #pragma unroll
    for (int s = 0; s < 2; s++) {
      int ii = wave * 2 + s;
      float a = (s == 0) ? a0 : a1;
      float dx = sti[0][ii] - tjx;
      float dy = sti[1][ii] - tjy;
      float dz = sti[2][ii] - tjz;
      sS[ii][jc + jj] = a * 0.17677669529663689f - (dx * dx + dy * dy + dz * dz);
    }
    __syncthreads();
  }

  #pragma unroll
  for (int s = 0; s < 2; s++) {
    int ii = wave * 2 + s;
    float vrow[6];
    float m = -1e30f;
    #pragma unroll
    for (int t = 0; t < 6; t++) { vrow[t] = sS[ii][t * 64 + lane]; m = fmaxf(m, vrow[t]); }
    #pragma unroll
    for (int off = 32; off >= 1; off >>= 1) m = fmaxf(m, __shfl_xor(m, off, 64));
    float ps = 0.f;
    #pragma unroll
    for (int t = 0; t < 6; t++) {
      float e = expf(vrow[t] - m);
      sS[ii][t * 64 + lane] = e;
      ps += e;
    }
    #pragma unroll
    for (int off = 32; off >= 1; off >>= 1) ps += __shfl_xor(ps, off, 64);
    if (lane == 0) sinv[ii] = 1.0f / ps;
  }
  __syncthreads();

  int ii = tid >> 5, dd = tid & 31;
  float o0 = 0.f, o1 = 0.f;
  for (int jc = 0; jc < N_; jc += 64) {
    for (int idx = tid; idx < 64 * DH_; idx += 256) {
      int jj = idx >> 5, d = idx & 31;
      sV[jj * DH_ + d] = vb[(size_t)(jc + jj) * D_ + d];
    }
    __syncthreads();
    #pragma unroll 8
    for (int jj = 0; jj < 64; jj += 2) {
      o0 = fmaf(sS[ii][jc + jj],     sV[jj * DH_ + dd],       o0);
      o1 = fmaf(sS[ii][jc + jj + 1], sV[(jj + 1) * DH_ + dd], o1);
    }
    __syncthreads();
  }
  AO[((size_t)(b * N_ + i0 + ii)) * D_ + h * DH_ + dd] = (o0 + o1) * sinv[ii];
}

// ---------------- fused pair LN-mean + head (shuffle-free pair phase) ----------------
// grid = M, 256 threads
__global__ void pair_head_kernel(const float* __restrict__ projc, const float* __restrict__ projcT,
                                 const float* __restrict__ relc, const float* __restrict__ relcT,
                                 const float* __restrict__ lnw, const float* __restrict__ lnb,
                                 const float* __restrict__ x,
                                 const float* __restrict__ Wf1, const float* __restrict__ bWf1,
                                 const float* __restrict__ Wf2, const float* __restrict__ bWf2,
                                 float* __restrict__ frames, float* __restrict__ tx,
                                 float* __restrict__ ty, float* __restrict__ tz) {
  const int M = B_ * N_;
  int row = blockIdx.x;            // b*N + i
  int b = row / N_;
  int i = row % N_;
  int tid = threadIdx.x;           // 256 = 4 waves
  int lane = tid & 63;
  int wave = tid >> 6;
  __shared__ float svpi[PD_];
  __shared__ float sr[N_];         // rinv per j
  __shared__ float red[4][PD_];
  __shared__ float sfeat[320];
  __shared__ float fred[2][128];
  __shared__ float sg[128];
  __shared__ float sraw[9];

  if (tid < PD_) svpi[tid] = projc[row * PD_ + tid];
  if (tid < D_) sfeat[tid] = x[(size_t)row * D_ + tid];
  __syncthreads();

  // ---- pass A: rinv[j] via thread-per-j (coalesced transposed reads, no shuffles) ----
  {
    int jA = tid;                  // 0..255
    int raA = jA - i; raA = raA < -64 ? -64 : (raA > 64 ? 64 : raA); raA += 64;
    const float* pA = projcT + b * N_ + jA;
    const float* rA = relcT + raA;
    float s2A = 0.f;
    #pragma unroll 8
    for (int c = 0; c < PD_; c++) {
      float dA = svpi[c] + pA[(size_t)c * M] + rA[c * RT_];
      s2A = fmaf(dA, dA, s2A);
    }
    sr[jA] = rsqrtf(s2A * (1.0f / PD_) + 1e-5f);
    if (tid < 128) {
      int jB = tid + 256;          // 256..383
      int raB = jB - i; raB = raB < -64 ? -64 : (raB > 64 ? 64 : raB); raB += 64;
      const float* pB = projcT + b * N_ + jB;
      const float* rB = relcT + raB;
      float s2B = 0.f;
      #pragma unroll 8
      for (int c = 0; c < PD_; c++) {
        float dB = svpi[c] + pB[(size_t)c * M] + rB[c * RT_];
        s2B = fmaf(dB, dB, s2B);
      }
      sr[jB] = rsqrtf(s2B * (1.0f / PD_) + 1e-5f);
    }
  }
  __syncthreads();

  // ---- pass B: per-channel accumulation (row-major coalesced, no shuffles) ----
  {
    float vpl = svpi[lane];
    const float* pb = projc + (size_t)b * N_ * PD_;
    float acc = 0.0f;
    for (int j = wave * 2; j < N_; j += 8) {
      int ja = j, jb = j + 1;
      int ra = ja - i; ra = ra < -64 ? -64 : (ra > 64 ? 64 : ra); ra += 64;
      int rb = jb - i; rb = rb < -64 ? -64 : (rb > 64 ? 64 : rb); rb += 64;
      float da = vpl + pb[ja * PD_ + lane] + relc[ra * PD_ + lane];
      float db = vpl + pb[jb * PD_ + lane] + relc[rb * PD_ + lane];
      acc = fmaf(da, sr[ja], fmaf(db, sr[jb], acc));
    }
    red[wave][lane] = acc;
  }
  __syncthreads();
  if (wave == 0) {
    float s = red[0][lane] + red[1][lane] + red[2][lane] + red[3][lane];
    sfeat[D_ + lane] = lnb[lane] + s * lnw[lane] * (1.0f / N_);
  }
  __syncthreads();

  // ---- fc1 silu (320 -> 128), 2 k-chunks x 128 cols ----
  int kc = tid >> 7, c = tid & 127;
  int koff = kc * 160;
  const float* wp = Wf1 + (size_t)koff * 128 + c;
  const float* s0 = sfeat + koff;
  float a0 = 0.f, a1 = 0.f, a2 = 0.f, a3 = 0.f;
  for (int kk = 0; kk < 160; kk += 4) {
    a0 = fmaf(s0[kk],     wp[(size_t)kk * 128],       a0);
    a1 = fmaf(s0[kk + 1], wp[(size_t)(kk + 1) * 128], a1);
    a2 = fmaf(s0[kk + 2], wp[(size_t)(kk + 2) * 128], a2);
    a3 = fmaf(s0[kk + 3], wp[(size_t)(kk + 3) * 128], a3);
  }
  fred[kc][c] = (a0 + a1) + (a2 + a3);
  __syncthreads();
  if (tid < 128) {
    float g = fred[0][tid] + fred[1][tid] + bWf1[tid];
    sg[tid] = g / (1.0f + expf(-g));
  }
  __syncthreads();

  // ---- fc2 (128 -> 9), rot6d, frame write ----
  if (tid < 9) {
    float b0 = 0.f, b1v = 0.f;
    for (int kk = 0; kk < 128; kk += 2) {
      b0  = fmaf(sg[kk],     Wf2[(kk)     * 9 + tid], b0);
      b1v = fmaf(sg[kk + 1], Wf2[(kk + 1) * 9 + tid], b1v);
    }
    sraw[tid] = bWf2[tid] + b0 + b1v;
  }
  __syncthreads();
  if (tid == 0) {
    float a1x = sraw[0], a1y = sraw[1], a1z = sraw[2];
    float a2x = sraw[3], a2y = sraw[4], a2z = sraw[5];
    float n1 = sqrtf(a1x * a1x + a1y * a1y + a1z * a1z + 1e-8f);
    float b1x = a1x / n1, b1y = a1y / n1, b1z = a1z / n1;
    float dp = b1x * a2x + b1y * a2y + b1z * a2z;
    float px = a2x - dp * b1x, py = a2y - dp * b1y, pz = a2z - dp * b1z;
    float n2 = sqrtf(px * px + py * py + pz * pz + 1e-8f);
    float b2x = px / n2, b2y = py / n2, b2z = pz / n2;
    float b3x = b1y * b2z - b1z * b2y;
    float b3y = b1z * b2x - b1x * b2z;
    float b3z = b1x * b2y - b1y * b2x;
    float* f = frames + row * 16;
    f[0]  = b1x; f[1]  = b1y; f[2]  = b1z; f[3]  = sraw[6];
    f[4]  = b2x; f[5]  = b2y; f[6]  = b2z; f[7]  = sraw[7];
    f[8]  = b3x; f[9]  = b3y; f[10] = b3z; f[11] = sraw[8];
    f[12] = 0.0f; f[13] = 0.0f; f[14] = 0.0f; f[15] = 1.0f;
    tx[row] = sraw[6];
    ty[row] = sraw[7];
    tz[row] = sraw[8];
  }
}

// ---------------- output ----------------
__global__ void write_out_kernel(const float* __restrict__ frames, const float* __restrict__ x,
                                 float* __restrict__ out) {
  int i = blockIdx.x * 256 + threadIdx.x;
  const int nf = B_ * N_ * 16;
  const int total = nf + B_ * N_ * D_;
  if (i < nf) out[i] = frames[i];
  else if (i < total) out[i] = x[i - nf];
}

extern "C" void kernel_launch(void* const* d_in, const int* in_sizes, int n_in,
                              void* d_out, int out_size, void* d_ws, size_t ws_size,
                              hipStream_t stream) {
  const int*   tokens    = (const int*)  d_in[0];
  const float* tok_emb   = (const float*)d_in[1];
  const float* emb_ln_w  = (const float*)d_in[2];
  const float* emb_ln_b  = (const float*)d_in[3];
  const float* Wq        = (const float*)d_in[4];
  const float* Wk        = (const float*)d_in[5];
  const float* Wv        = (const float*)d_in[6];
  const float* Wo        = (const float*)d_in[7];
  const float* bo        = (const float*)d_in[8];
  const float* attn_ln_w = (const float*)d_in[9];
  const float* attn_ln_b = (const float*)d_in[10];
  const float* ff_ln_w   = (const float*)d_in[11];
  const float* ff_ln_b   = (const float*)d_in[12];
  const float* W1        = (const float*)d_in[13];
  const float* b1        = (const float*)d_in[14];
  const float* W2        = (const float*)d_in[15];
  const float* b2        = (const float*)d_in[16];
  const float* Wop       = (const float*)d_in[17];
  const float* bop       = (const float*)d_in[18];
  const float* relpos    = (const float*)d_in[19];
  const float* pair_ln_w = (const float*)d_in[20];
  const float* pair_ln_b = (const float*)d_in[21];
  const float* Wf1       = (const float*)d_in[22];
  const float* bWf1      = (const float*)d_in[23];
  const float* Wf2       = (const float*)d_in[24];
  const float* bWf2      = (const float*)d_in[25];

  const int M = B_ * N_;           // 768
  const int XE = M * D_;           // 196608
  float* ws     = (float*)d_ws;
  float* frames = ws;                      // 12288
  float* projc  = frames + M * 16;         // 49152
  float* projcT = projc  + M * PD_;        // 49152
  float* relc   = projcT + M * PD_;        // 8256 (pad 8320)
  float* relcT  = relc   + 8320;           // 64*132 = 8448
  float* tx     = relcT  + 8448;           // 768
  float* ty     = tx     + M;              // 768
  float* tz     = ty     + M;              // 768
  float* x      = tz     + M;              // XE
  float* q      = x  + XE;                 // XE
  float* kt     = q  + XE;                 // XE (K transposed [b,h,d,j])
  float* v      = kt + XE;                 // XE
  float* ao     = v  + XE;                 // XE
  float* f      = q;                       // alias: q..ao = 4*XE (ff intermediate)

  prologue_kernel<<<M, 256, 0, stream>>>(tokens, tok_emb, emb_ln_w, emb_ln_b, relpos,
                                         x, frames, tx, ty, tz, relc, relcT);
  qkv_kernel<<<(M / GR) * 12, 256, 0, stream>>>(x, Wq, Wk, Wv, q, kt, v);

  const size_t lds_ff2 = (GR * 1024 + 1024) * sizeof(float);   // 20 KB

  for (int l = 0; l < L_; l++) {
    attn_kernel<<<B_ * H_ * (N_ / IT), 256, 0, stream>>>(q, kt, v, tx, ty, tz, ao);
    wo_ln_kernel<<<M / 2, 256, 0, stream>>>(ao, Wo + (size_t)l * D_ * D_, bo + l * D_,
                                            attn_ln_w + l * D_, attn_ln_b + l * D_, x);
    ff1_kernel<<<(M / GR) * 8, 256, 0, stream>>>(x, ff_ln_w + l * D_, ff_ln_b + l * D_,
                                                 W1 + (size_t)l * D_ * 1024, b1 + l * 1024, f);
    gemm4t_kernel<<<(M / GR) * 8, 256, lds_ff2, stream>>>(
        f, W2 + (size_t)l * 1024 * D_, b2 + l * D_, x, x, 1024, D_);
    if (l < L_ - 1) {
      int lq = l + 1;
      proj_qkv_kernel<<<M + (M / GR) * 12, 256, 0, stream>>>(
          x, Wop, bop, projc, projcT,
          Wq + (size_t)lq * D_ * D_, Wk + (size_t)lq * D_ * D_, Wv + (size_t)lq * D_ * D_,
          q, kt, v);
    } else {
      proj_qkv_kernel<<<M, 256, 0, stream>>>(x, Wop, bop, projc, projcT, Wq, Wk, Wv, q, kt, v);
    }
    pair_head_kernel<<<M, 256, 0, stream>>>(projc, projcT, relc, relcT, pair_ln_w, pair_ln_b,
                                            x, Wf1, bWf1, Wf2, bWf2, frames, tx, ty, tz);
  }

  const int total = B_ * N_ * 16 + B_ * N_ * D_;
  write_out_kernel<<<(total + 255) / 256, 256, 0, stream>>>(frames, x, (float*)d_out);
}